// Round 1
// 1403.815 us; speedup vs baseline: 1.0278x; 1.0278x over previous
//
#include <hip/hip_runtime.h>
#include <hip/hip_bf16.h>
#include <float.h>

typedef __hip_bfloat16 bf16;
typedef __attribute__((ext_vector_type(8))) __bf16 bfrag;   // MFMA A/B operand (4 VGPRs)
typedef __attribute__((ext_vector_type(4))) float f32x4;    // MFMA C/D operand

#define B_ 32
#define C_ 312
#define N_ 1024
#define H_ 8
#define D_ 128
#define SD_ 78
#define BC_ (B_ * C_)      // 9984
#define BH_ (B_ * H_)      // 256

__device__ __forceinline__ float bf2f(bf16 x) { return __bfloat162float(x); }
__device__ __forceinline__ bf16 f2bf(float x) { return __float2bfloat16(x); }
__device__ __forceinline__ float hswish(float x) {
    return x * fminf(fmaxf(x + 3.0f, 0.0f), 6.0f) * (1.0f / 6.0f);
}

// ---------------- LayerNorm (stats only; affine folded into GEMM A-load) ----
__global__ void ln_kernel(const float* __restrict__ x, bf16* __restrict__ xn) {
    int r = blockIdx.x;
    int t = threadIdx.x;
    const float* xr = x + (size_t)r * N_;
    float s = 0.f, sq = 0.f;
    for (int i = t; i < N_; i += 256) { float f = xr[i]; s += f; sq += f * f; }
    __shared__ float rs[256], rq[256];
    rs[t] = s; rq[t] = sq; __syncthreads();
    for (int o = 128; o > 0; o >>= 1) {
        if (t < o) { rs[t] += rs[t + o]; rq[t] += rq[t + o]; }
        __syncthreads();
    }
    float mu = rs[0] * (1.0f / N_);
    float var = rq[0] * (1.0f / N_) - mu * mu;
    float rstd = rsqrtf(var + 1e-5f);
    bf16* xo = xn + (size_t)r * N_;
    for (int i = t; i < N_; i += 256) xo[i] = f2bf((xr[i] - mu) * rstd);
}

// ---------------- MFMA GEMM: C[M,1024] = A' * W^T (+bias) -------------------
#define GLDA 72   // LDS row stride (bf16 elems): 64 + 8 pad
template <bool OUTF32>
__global__ __launch_bounds__(256) void mfma_gemm_kernel(
        const bf16* __restrict__ A_,
        const float* __restrict__ G,
        const float* __restrict__ Bv,
        const float* __restrict__ W,
        const float* __restrict__ bias,
        void* __restrict__ Cout) {
    const int K = 1024, Nout = 1024;
    __shared__ __bf16 sA[128 * GLDA];
    __shared__ __bf16 sB[128 * GLDA];
    const __bf16* A = reinterpret_cast<const __bf16*>(A_);

    int t = threadIdx.x;
    int lane = t & 63, wave = t >> 6;
    int wm = (wave >> 1) * 64, wn = (wave & 1) * 64;
    int quad = lane >> 4, l15 = lane & 15;
    int m0 = blockIdx.y * 128, n0 = blockIdx.x * 128;

    f32x4 acc[4][4];
#pragma unroll
    for (int i = 0; i < 4; i++)
#pragma unroll
        for (int j = 0; j < 4; j++) acc[i][j] = (f32x4)(0.f);

    for (int kt = 0; kt < 16; kt++) {
        int k0 = kt * 64;
#pragma unroll
        for (int cc = 0; cc < 4; cc++) {
            int c = t + cc * 256;
            int row = c >> 3, seg = c & 7;
            bfrag av = *reinterpret_cast<const bfrag*>(A + (size_t)(m0 + row) * K + k0 + seg * 8);
            if (G) {
                bfrag bv2;
#pragma unroll
                for (int j = 0; j < 8; j++) {
                    float fa = (float)av[j];
                    bv2[j] = (__bf16)(fa * G[k0 + seg * 8 + j] + Bv[k0 + seg * 8 + j]);
                }
                av = bv2;
            }
            *reinterpret_cast<bfrag*>(&sA[row * GLDA + seg * 8]) = av;
        }
#pragma unroll
        for (int cc = 0; cc < 4; cc++) {
            int c = t + cc * 256;
            int row = c >> 3, seg = c & 7;
            const float* wp = W + (size_t)(n0 + row) * K + k0 + seg * 8;
            float4 w0 = *reinterpret_cast<const float4*>(wp);
            float4 w1 = *reinterpret_cast<const float4*>(wp + 4);
            bfrag bv2;
            bv2[0] = (__bf16)w0.x; bv2[1] = (__bf16)w0.y; bv2[2] = (__bf16)w0.z; bv2[3] = (__bf16)w0.w;
            bv2[4] = (__bf16)w1.x; bv2[5] = (__bf16)w1.y; bv2[6] = (__bf16)w1.z; bv2[7] = (__bf16)w1.w;
            *reinterpret_cast<bfrag*>(&sB[row * GLDA + seg * 8]) = bv2;
        }
        __syncthreads();
#pragma unroll
        for (int kk = 0; kk < 2; kk++) {
            bfrag af[4], bf[4];
#pragma unroll
            for (int mt = 0; mt < 4; mt++)
                af[mt] = *reinterpret_cast<const bfrag*>(&sA[(wm + mt * 16 + l15) * GLDA + kk * 32 + quad * 8]);
#pragma unroll
            for (int nt = 0; nt < 4; nt++)
                bf[nt] = *reinterpret_cast<const bfrag*>(&sB[(wn + nt * 16 + l15) * GLDA + kk * 32 + quad * 8]);
#pragma unroll
            for (int mt = 0; mt < 4; mt++)
#pragma unroll
                for (int nt = 0; nt < 4; nt++)
                    acc[mt][nt] = __builtin_amdgcn_mfma_f32_16x16x32_bf16(af[mt], bf[nt], acc[mt][nt], 0, 0, 0);
        }
        __syncthreads();
    }
#pragma unroll
    for (int mt = 0; mt < 4; mt++) {
#pragma unroll
        for (int nt = 0; nt < 4; nt++) {
            int col = n0 + wn + nt * 16 + l15;
            float bb = bias ? bias[col] : 0.f;
#pragma unroll
            for (int r = 0; r < 4; r++) {
                int row = m0 + wm + mt * 16 + quad * 4 + r;
                float v = acc[mt][nt][r] + bb;
                if (OUTF32) ((float*)Cout)[(size_t)row * Nout + col] = v;
                else        ((bf16*)Cout)[(size_t)row * Nout + col] = f2bf(v);
            }
        }
    }
}

// ---------------- aggregator pieces -----------------------------------------
__global__ void seg0_kernel(const bf16* __restrict__ t, bf16* __restrict__ th,
                            const float* __restrict__ g, const float* __restrict__ b,
                            const float* __restrict__ m, const float* __restrict__ v) {
    int bc = blockIdx.x;
    int bi = bc / SD_, c = bc % SD_;
    float inv = g[c] * rsqrtf(v[c] + 1e-5f);
    float mm = m[c], bb = b[c];
    const bf16* tp = t + ((size_t)bi * C_ + c) * N_;
    bf16* base = th + (size_t)bi * H_ * C_ * D_;
    for (int n = threadIdx.x; n < N_; n += 256) {
        float y = hswish((bf2f(tp[n]) - mm) * inv + bb);
        base[((n >> 7) * C_ + c) * D_ + (n & 127)] = f2bf(y);
    }
}

template <int KS>
__global__ void dw_kernel(const bf16* __restrict__ t, int cOff,
                          const float* __restrict__ dw, float* __restrict__ outp) {
    int bc = blockIdx.x;
    int bi = bc / SD_, c = bc % SD_;
    const bf16* tp = t + ((size_t)bi * C_ + cOff + c) * N_;
    float w[KS * KS];
#pragma unroll
    for (int q = 0; q < KS * KS; q++) w[q] = dw[c * KS * KS + q];
    float* op = outp + ((size_t)bi * SD_ + c) * N_;
    const int P = KS / 2;
    for (int n = threadIdx.x; n < N_; n += 256) {
        int i = n >> 5, j = n & 31;
        float acc = 0.f;
#pragma unroll
        for (int di = 0; di < KS; di++) {
            int ii = i + di - P;
            if (ii < 0 || ii > 31) continue;
#pragma unroll
            for (int dj = 0; dj < KS; dj++) {
                int jj = j + dj - P;
                if (jj < 0 || jj > 31) continue;
                acc += bf2f(tp[ii * 32 + jj]) * w[di * KS + dj];
            }
        }
        op[n] = acc;
    }
}

template <int MODE>
__global__ void pw_kernel(const float* __restrict__ inp, const float* __restrict__ pw,
                          const float* __restrict__ g, const float* __restrict__ b,
                          const float* __restrict__ m, const float* __restrict__ v,
                          int cOff, bf16* __restrict__ th, float* __restrict__ rawOut) {
    int bo = blockIdx.x;
    int bi = bo / SD_, o = bo % SD_;
    __shared__ float wrow[SD_];
    for (int c = threadIdx.x; c < SD_; c += 256) wrow[c] = pw[o * SD_ + c];
    __syncthreads();
    const float* ip = inp + (size_t)bi * SD_ * N_;
    int t = threadIdx.x;
    float acc[4] = {0.f, 0.f, 0.f, 0.f};
    for (int c = 0; c < SD_; c++) {
        const float* row = ip + (size_t)c * N_;
        float wc = wrow[c];
#pragma unroll
        for (int r = 0; r < 4; r++) acc[r] += row[t + 256 * r] * wc;
    }
    if (MODE == 0) {
        float inv = g[o] * rsqrtf(v[o] + 1e-5f);
        float mm = m[o], bb = b[o];
        bf16* base = th + (size_t)bi * H_ * C_ * D_;
#pragma unroll
        for (int r = 0; r < 4; r++) {
            int n = t + 256 * r;
            float y = hswish((acc[r] - mm) * inv + bb);
            base[((n >> 7) * C_ + cOff + o) * D_ + (n & 127)] = f2bf(y);
        }
    } else {
        float* opr = rawOut + ((size_t)bi * SD_ + o) * N_;
#pragma unroll
        for (int r = 0; r < 4; r++) opr[t + 256 * r] = acc[r];
    }
}

__global__ void gn_stats_kernel(const float* __restrict__ tmp2, float* __restrict__ stats) {
    int bg = blockIdx.x;
    int bi = bg >> 1, grp = bg & 1;
    const float* p = tmp2 + (size_t)bi * SD_ * N_ + (size_t)grp * 39 * N_;
    float s = 0.f, sq = 0.f;
    const int TOT = 39 * N_;
    for (int i = threadIdx.x; i < TOT; i += 256) { float f = p[i]; s += f; sq += f * f; }
    __shared__ float rs[256], rq[256];
    rs[threadIdx.x] = s; rq[threadIdx.x] = sq; __syncthreads();
    for (int o = 128; o > 0; o >>= 1) {
        if (threadIdx.x < o) { rs[threadIdx.x] += rs[threadIdx.x + o]; rq[threadIdx.x] += rq[threadIdx.x + o]; }
        __syncthreads();
    }
    if (threadIdx.x == 0) {
        float mu = rs[0] / (float)TOT;
        float var = rq[0] / (float)TOT - mu * mu;
        stats[bg * 2] = mu;
        stats[bg * 2 + 1] = rsqrtf(var + 1e-5f);
    }
}

__global__ void gn_apply_kernel(const float* __restrict__ tmp2, const float* __restrict__ stats,
                                const float* __restrict__ gg, const float* __restrict__ gb,
                                bf16* __restrict__ th) {
    int bc = blockIdx.x;
    int bi = bc / SD_, c = bc % SD_;
    int grp = c / 39;
    float mu = stats[(bi * 2 + grp) * 2];
    float rstd = stats[(bi * 2 + grp) * 2 + 1];
    float sc = gg[c] * rstd;
    float of = gb[c] - mu * sc;
    const float* p = tmp2 + ((size_t)bi * SD_ + c) * N_;
    bf16* base = th + (size_t)bi * H_ * C_ * D_;
    for (int n = threadIdx.x; n < N_; n += 256) {
        float y = hswish(p[n] * sc + of);
        base[((n >> 7) * C_ + 234 + c) * D_ + (n & 127)] = f2bf(y);
    }
}

// ---- MFMA scores + GELU + scale + softmax, fused ---------------------------
// v2: 512 threads / 8 waves. Wave (wm,wn): wm = 16-row m-tile (4 of them),
// wn = 160-col half. acc[10] (40 VGPR) instead of acc[20] (80) -> VGPR <= 128
// -> 4 waves/SIMD with 2 blocks/CU resident (LDS ~62 KB): occupancy 2x.
// Cross-wave softmax combine (wn pair) via 1 KB LDS.
#define SLDA 136
__global__ __launch_bounds__(512, 4) void attn_mfma_kernel(
        const bf16* __restrict__ qh_, const bf16* __restrict__ kh_,
        float* __restrict__ attnOut) {
    __shared__ __bf16 sQ[64 * SLDA];
    __shared__ __bf16 sK[160 * SLDA];
    __shared__ float smax[64][2];
    __shared__ float ssum[64][2];
    const __bf16* qh = reinterpret_cast<const __bf16*>(qh_);
    const __bf16* kh = reinterpret_cast<const __bf16*>(kh_);

    int strip = blockIdx.x;     // 5 strips of 64 Q-rows
    int bh = blockIdx.y;
    int t = threadIdx.x;
    int lane = t & 63, wave = t >> 6;   // 8 waves
    int quad = lane >> 4, l15 = lane & 15;
    int wm = wave >> 1;         // 0..3: 16-row m-tile
    int wn = wave & 1;          // 0..1: 160-col half assignment

    // stage Q strip: 64 rows x 128 (rows >= 312 clamped; never stored)
#pragma unroll
    for (int cc = 0; cc < 2; cc++) {
        int c = t + cc * 512;
        int row = c >> 4, seg = c & 15;
        int src = strip * 64 + row; if (src > 311) src = 311;
        bfrag v = *reinterpret_cast<const bfrag*>(qh + ((size_t)bh * C_ + src) * D_ + seg * 8);
        *reinterpret_cast<bfrag*>(&sQ[row * SLDA + seg * 8]) = v;
    }

    f32x4 acc[10];
#pragma unroll
    for (int i = 0; i < 10; i++) acc[i] = (f32x4)(0.f);

    bfrag af[4];
    bool afLoaded = false;

    for (int half = 0; half < 2; half++) {
        if (half) __syncthreads();   // all waves done reading sK of prev half
        // stage K rows [half*160, +160); zero-pad c >= 312
        for (int cc = 0; cc < 5; cc++) {
            int c = t + cc * 512;
            int row = c >> 4, seg = c & 15;
            int src = half * 160 + row;
            bfrag v;
            if (src < C_) {
                v = *reinterpret_cast<const bfrag*>(kh + ((size_t)bh * C_ + src) * D_ + seg * 8);
            } else {
#pragma unroll
                for (int j = 0; j < 8; j++) v[j] = (__bf16)0.f;
            }
            *reinterpret_cast<bfrag*>(&sK[row * SLDA + seg * 8]) = v;
        }
        __syncthreads();
        if (!afLoaded) {
#pragma unroll
            for (int ks = 0; ks < 4; ks++)
                af[ks] = *reinterpret_cast<const bfrag*>(&sQ[(wm * 16 + l15) * SLDA + ks * 32 + quad * 8]);
            afLoaded = true;
        }
#pragma unroll
        for (int ks = 0; ks < 4; ks++) {
#pragma unroll
            for (int jj = 0; jj < 5; jj++) {
                int lr = (wn * 5 + jj) * 16 + l15;   // local sK row
                bfrag bf = *reinterpret_cast<const bfrag*>(&sK[lr * SLDA + ks * 32 + quad * 8]);
                acc[half * 5 + jj] = __builtin_amdgcn_mfma_f32_16x16x32_bf16(af[ks], bf, acc[half * 5 + jj], 0, 0, 0);
            }
        }
    }

    // acc[a] holds col-tile gt = (a/5)*10 + wn*5 + (a%5); C-layout row = quad*4+r
    const float scale = 0.08838834764831845f;
    const float inv_sqrt2 = 0.7071067811865475f;
#pragma unroll
    for (int a = 0; a < 10; a++) {
        int gt = (a / 5) * 10 + wn * 5 + (a % 5);
        int col = gt * 16 + l15;
#pragma unroll
        for (int r = 0; r < 4; r++) {
            float v = acc[a][r];
            float ge = 0.5f * v * (1.0f + erff(v * inv_sqrt2));
            float s = ge * scale;
            if (col >= C_) s = -FLT_MAX;
            acc[a][r] = s;
        }
    }
    // per-row max over this wave's 10 tiles, reduce across 16-lane group
    float mx[4];
#pragma unroll
    for (int r = 0; r < 4; r++) {
        float m = -FLT_MAX;
#pragma unroll
        for (int a = 0; a < 10; a++) m = fmaxf(m, acc[a][r]);
        for (int o = 1; o < 16; o <<= 1) m = fmaxf(m, __shfl_xor(m, o));
        mx[r] = m;
    }
    if (l15 == 0) {
#pragma unroll
        for (int r = 0; r < 4; r++) smax[wm * 16 + quad * 4 + r][wn] = mx[r];
    }
    __syncthreads();
    float sm[4];
#pragma unroll
    for (int r = 0; r < 4; r++) {
        int row = wm * 16 + quad * 4 + r;
        float m = fmaxf(smax[row][0], smax[row][1]);
        float s = 0.f;
#pragma unroll
        for (int a = 0; a < 10; a++) {
            float e = __expf(acc[a][r] - m);
            acc[a][r] = e;
            s += e;
        }
        for (int o = 1; o < 16; o <<= 1) s += __shfl_xor(s, o);
        sm[r] = s;
    }
    if (l15 == 0) {
#pragma unroll
        for (int r = 0; r < 4; r++) ssum[wm * 16 + quad * 4 + r][wn] = sm[r];
    }
    __syncthreads();
#pragma unroll
    for (int r = 0; r < 4; r++) {
        int row = wm * 16 + quad * 4 + r;
        float inv = 1.0f / (ssum[row][0] + ssum[row][1]);
        int grow = strip * 64 + row;
        if (grow >= C_) continue;
        float* ao = attnOut + ((size_t)bh * C_ + grow) * C_;
#pragma unroll
        for (int a = 0; a < 10; a++) {
            int gt = (a / 5) * 10 + wn * 5 + (a % 5);
            int col = gt * 16 + l15;
            if (col < C_) ao[col] = acc[a][r] * inv;
        }
    }
}

// ---- MFMA attn @ V -> ctx (scrambled layout) --------------------------------
// Block = (bh, 32-row strip). P staged fp32->bf16 (k padded to 320 w/ zeros);
// V staged in frag-order LDS in two 160-row k-halves. 4 waves: 2 m-tiles x 2 n-halves.
#define PLDA 328   // 320 + 8 pad: row stride 656B = 164 dw, %32 = 4 banks
__global__ __launch_bounds__(256) void av_mfma_kernel(
        const float* __restrict__ attn, const bf16* __restrict__ vh_,
        bf16* __restrict__ ctx) {
    __shared__ __bf16 sP[32 * PLDA];        // 20992 B
    __shared__ __bf16 sV[5 * 8 * 64 * 8];   // 40960 B  [(kt,nt,lane) x 8]
    const __bf16* vh = reinterpret_cast<const __bf16*>(vh_);
    int strip = blockIdx.x;                 // 0..9 -> rows strip*32..+31
    int bh = blockIdx.y;
    int t = threadIdx.x;
    int lane = t & 63, wave = t >> 6;
    int quad = lane >> 4, l15 = lane & 15;
    int mt = wave & 1;                      // m-tile (16 rows)
    int nh = wave >> 1;                     // n-half (4 n-tiles of 16 cols)

    // stage P strip: fp32 attn -> bf16, cols padded to 320 with zeros
    for (int g = t; g < 32 * 80; g += 256) {
        int row = g / 80, col4 = g % 80;
        int src = strip * 32 + row; if (src > 311) src = 311;
        __bf16 pk[4];
        if (col4 < 78) {
            float4 a4 = *reinterpret_cast<const float4*>(attn + ((size_t)bh * C_ + src) * C_ + col4 * 4);
            pk[0] = (__bf16)a4.x; pk[1] = (__bf16)a4.y; pk[2] = (__bf16)a4.z; pk[3] = (__bf16)a4.w;
        } else {
            pk[0] = pk[1] = pk[2] = pk[3] = (__bf16)0.f;
        }
        *reinterpret_cast<uint2*>(&sP[row * PLDA + col4 * 4]) = *reinterpret_cast<const uint2*>(pk);
    }

    f32x4 acc[4];
#pragma unroll
    for (int i = 0; i < 4; i++) acc[i] = (f32x4)(0.f);

    for (int half = 0; half < 2; half++) {
        if (half) __syncthreads();   // all waves done reading sV of prev half
        // stage V rows [half*160, +160) into frag-order sV; zero-pad c >= 312
        for (int g = t; g < 160 * 16; g += 256) {
            int cl = g >> 4, dseg = g & 15;
            int src = half * 160 + cl;
            bfrag v;
            if (src < C_) {
                v = *reinterpret_cast<const bfrag*>(vh + ((size_t)bh * C_ + src) * D_ + dseg * 8);
            } else {
#pragma unroll
                for (int j = 0; j < 8; j++) v[j] = (__bf16)0.f;
            }
            int kt = cl >> 5, q2 = (cl >> 3) & 3, j = cl & 7;
#pragma unroll
            for (int j2 = 0; j2 < 8; j2++) {
                int d = dseg * 8 + j2;
                int nt = d >> 4, dl = d & 15;
                sV[(((kt * 8 + nt) * 64) + q2 * 16 + dl) * 8 + j] = v[j2];
            }
        }
        __syncthreads();
#pragma unroll
        for (int kt = 0; kt < 5; kt++) {
            bfrag a = *reinterpret_cast<const bfrag*>(
                &sP[(mt * 16 + l15) * PLDA + half * 160 + kt * 32 + quad * 8]);
#pragma unroll
            for (int ntl = 0; ntl < 4; ntl++) {
                int ntg = nh * 4 + ntl;
                bfrag b = *reinterpret_cast<const bfrag*>(&sV[(((kt * 8 + ntg) * 64) + lane) * 8]);
                acc[ntl] = __builtin_amdgcn_mfma_f32_16x16x32_bf16(a, b, acc[ntl], 0, 0, 0);
            }
        }
    }

    // epilogue: ctx[b, h*39 + c/8, (c%8)*128 + d], C-layout row = quad*4+r
    int b = bh >> 3, h = bh & 7;
#pragma unroll
    for (int ntl = 0; ntl < 4; ntl++) {
        int d = nh * 64 + ntl * 16 + l15;
#pragma unroll
        for (int r = 0; r < 4; r++) {
            int c = strip * 32 + mt * 16 + quad * 4 + r;
            if (c < C_) {
                size_t oi = ((size_t)b * C_ + h * 39 + (c >> 3)) * N_ + ((c & 7) << 7) + d;
                ctx[oi] = f2bf(acc[ntl][r]);
            }
        }
    }
}

// ---------------- L2 row norm (fp32 out) -------------------------------------
__global__ void norm_kernel(const float* __restrict__ out3, float* __restrict__ outp) {
    int r = blockIdx.x;
    const float* p = out3 + (size_t)r * N_;
    float sq = 0.f;
    for (int i = threadIdx.x; i < N_; i += 256) { float f = p[i]; sq += f * f; }
    __shared__ float rq[256];
    rq[threadIdx.x] = sq; __syncthreads();
    for (int o = 128; o > 0; o >>= 1) {
        if (threadIdx.x < o) rq[threadIdx.x] += rq[threadIdx.x + o];
        __syncthreads();
    }
    float inv = 1.0f / fmaxf(sqrtf(rq[0]), 1e-12f);
    float* po = outp + (size_t)r * N_;
    for (int i = threadIdx.x; i < N_; i += 256) po[i] = p[i] * inv;
}

// ---------------- host orchestration ----------------------------------------
extern "C" void kernel_launch(void* const* d_in, const int* in_sizes, int n_in,
                              void* d_out, int out_size, void* d_ws, size_t ws_size,
                              hipStream_t stream) {
    const float* x      = (const float*)d_in[0];
    const float* ln_q_g = (const float*)d_in[3];
    const float* ln_q_b = (const float*)d_in[4];
    const float* ln_k_g = (const float*)d_in[5];
    const float* ln_k_b = (const float*)d_in[6];
    const float* ln_v_g = (const float*)d_in[7];
    const float* ln_v_b = (const float*)d_in[8];
    const float* w_q    = (const float*)d_in[9];
    const float* w_k    = (const float*)d_in[10];
    const float* w_v    = (const float*)d_in[11];
    const float* w_proj = (const float*)d_in[12];
    const float* b_proj = (const float*)d_in[13];
    const float* dw0    = (const float*)d_in[14];
    const float* pw0    = (const float*)d_in[15];
    const float* gn_g   = (const float*)d_in[16];
    const float* gn_b   = (const float*)d_in[17];
    const float* dw1    = (const float*)d_in[18];
    const float* pw1    = (const float*)d_in[19];
    const float* dw2    = (const float*)d_in[20];
    const float* pw2    = (const float*)d_in[21];
    const float* bn0_g  = (const float*)d_in[22];
    const float* bn0_b  = (const float*)d_in[23];
    const float* bn0_m  = (const float*)d_in[24];
    const float* bn0_v  = (const float*)d_in[25];
    const float* bn1_g  = (const float*)d_in[26];
    const float* bn1_b  = (const float*)d_in[27];
    const float* bn1_m  = (const float*)d_in[28];
    const float* bn1_v  = (const float*)d_in[29];
    const float* bn2_g  = (const float*)d_in[30];
    const float* bn2_b  = (const float*)d_in[31];
    const float* bn2_m  = (const float*)d_in[32];
    const float* bn2_v  = (const float*)d_in[33];

    char* ws = (char*)d_ws;
    size_t off = 0;
    auto alloc = [&](size_t bytes) {
        void* p = ws + off;
        off = (off + bytes + 255) & ~(size_t)255;
        return p;
    };
    const size_t BF_BYTES = (size_t)BC_ * N_ * sizeof(bf16);
    bf16*  xn   = (bf16*)alloc(BF_BYTES);
    bf16*  qb   = (bf16*)alloc(BF_BYTES);
    bf16*  kb   = (bf16*)alloc(BF_BYTES);
    bf16*  vb   = (bf16*)alloc(BF_BYTES);
    float* tmp1 = (float*)alloc((size_t)B_ * SD_ * N_ * sizeof(float));
    float* tmp2 = (float*)alloc((size_t)B_ * SD_ * N_ * sizeof(float));
    float* gnst = (float*)alloc(512);
    bf16* qh  = xn;
    bf16* kh  = qb;
    bf16* vh  = kb;
    bf16* ctx = vb;
    float* out3 = (float*)xn;   // aliases xn+qb (dead after attn/av)

    float* out_main = (float*)d_out;
    float* attn_out = out_main + (size_t)BC_ * N_;

    dim3 gemm_grid(8, 78);

    hipLaunchKernelGGL(ln_kernel, dim3(BC_), dim3(256), 0, stream, x, xn);
    hipLaunchKernelGGL((mfma_gemm_kernel<false>), gemm_grid, dim3(256), 0, stream,
                       xn, ln_q_g, ln_q_b, w_q, (const float*)nullptr, (void*)qb);
    hipLaunchKernelGGL((mfma_gemm_kernel<false>), gemm_grid, dim3(256), 0, stream,
                       xn, ln_k_g, ln_k_b, w_k, (const float*)nullptr, (void*)kb);
    hipLaunchKernelGGL((mfma_gemm_kernel<false>), gemm_grid, dim3(256), 0, stream,
                       xn, ln_v_g, ln_v_b, w_v, (const float*)nullptr, (void*)vb);

    const bf16* tins[3] = {qb, kb, vb};
    bf16* thouts[3] = {qh, kh, vh};
    for (int i = 0; i < 3; i++) {
        const bf16* t = tins[i];
        bf16* th = thouts[i];
        dim3 g2496(B_ * SD_);
        hipLaunchKernelGGL(seg0_kernel, g2496, dim3(256), 0, stream,
                           t, th, bn0_g, bn0_b, bn0_m, bn0_v);
        hipLaunchKernelGGL((dw_kernel<3>), g2496, dim3(256), 0, stream, t, SD_, dw1, tmp1);
        hipLaunchKernelGGL((pw_kernel<0>), g2496, dim3(256), 0, stream,
                           tmp1, pw1, bn1_g, bn1_b, bn1_m, bn1_v, SD_, th, (float*)nullptr);
        hipLaunchKernelGGL((dw_kernel<5>), g2496, dim3(256), 0, stream, t, 2 * SD_, dw2, tmp1);
        hipLaunchKernelGGL((pw_kernel<0>), g2496, dim3(256), 0, stream,
                           tmp1, pw2, bn2_g, bn2_b, bn2_m, bn2_v, 2 * SD_, th, (float*)nullptr);
        hipLaunchKernelGGL((dw_kernel<3>), g2496, dim3(256), 0, stream, t, 3 * SD_, dw0, tmp1);
        hipLaunchKernelGGL((pw_kernel<1>), g2496, dim3(256), 0, stream,
                           tmp1, pw0, (const float*)nullptr, (const float*)nullptr,
                           (const float*)nullptr, (const float*)nullptr, 0, (bf16*)nullptr, tmp2);
        hipLaunchKernelGGL(gn_stats_kernel, dim3(B_ * 2), dim3(256), 0, stream, tmp2, gnst);
        hipLaunchKernelGGL(gn_apply_kernel, g2496, dim3(256), 0, stream, tmp2, gnst, gn_g, gn_b, th);
    }

    hipLaunchKernelGGL(attn_mfma_kernel, dim3(5, BH_), dim3(512), 0, stream, qh, kh, attn_out);
    hipLaunchKernelGGL(av_mfma_kernel, dim3(10, BH_), dim3(256), 0, stream, attn_out, vh, ctx);
    hipLaunchKernelGGL((mfma_gemm_kernel<true>), gemm_grid, dim3(256), 0, stream,
                       ctx, (const float*)nullptr, (const float*)nullptr, w_proj, b_proj,
                       (void*)out3);
    hipLaunchKernelGGL(norm_kernel, dim3(BC_), dim3(256), 0, stream, out3, out_main);
}

// Round 3
// 1341.547 us; speedup vs baseline: 1.0755x; 1.0464x over previous
//
#include <hip/hip_runtime.h>
#include <hip/hip_bf16.h>
#include <float.h>

typedef __hip_bfloat16 bf16;
typedef __attribute__((ext_vector_type(8))) __bf16 bfrag;   // MFMA A/B operand (4 VGPRs)
typedef __attribute__((ext_vector_type(4))) float f32x4;    // MFMA C/D operand

#define B_ 32
#define C_ 312
#define N_ 1024
#define H_ 8
#define D_ 128
#define SD_ 78
#define BC_ (B_ * C_)      // 9984
#define BH_ (B_ * H_)      // 256

__device__ __forceinline__ float bf2f(bf16 x) { return __bfloat162float(x); }
__device__ __forceinline__ bf16 f2bf(float x) { return __float2bfloat16(x); }
__device__ __forceinline__ float hswish(float x) {
    return x * fminf(fmaxf(x + 3.0f, 0.0f), 6.0f) * (1.0f / 6.0f);
}

// ---------------- LayerNorm (stats only; affine folded into GEMM A-load) ----
__global__ void ln_kernel(const float* __restrict__ x, bf16* __restrict__ xn) {
    int r = blockIdx.x;
    int t = threadIdx.x;
    const float* xr = x + (size_t)r * N_;
    float s = 0.f, sq = 0.f;
    for (int i = t; i < N_; i += 256) { float f = xr[i]; s += f; sq += f * f; }
    __shared__ float rs[256], rq[256];
    rs[t] = s; rq[t] = sq; __syncthreads();
    for (int o = 128; o > 0; o >>= 1) {
        if (t < o) { rs[t] += rs[t + o]; rq[t] += rq[t + o]; }
        __syncthreads();
    }
    float mu = rs[0] * (1.0f / N_);
    float var = rq[0] * (1.0f / N_) - mu * mu;
    float rstd = rsqrtf(var + 1e-5f);
    bf16* xo = xn + (size_t)r * N_;
    for (int i = t; i < N_; i += 256) xo[i] = f2bf((xr[i] - mu) * rstd);
}

// ---------------- MFMA GEMM: C[M,1024] = A' * W^T (+bias) -------------------
#define GLDA 72   // LDS row stride (bf16 elems): 64 + 8 pad
template <bool OUTF32>
__global__ __launch_bounds__(256) void mfma_gemm_kernel(
        const bf16* __restrict__ A_,
        const float* __restrict__ G,
        const float* __restrict__ Bv,
        const float* __restrict__ W,
        const float* __restrict__ bias,
        void* __restrict__ Cout) {
    const int K = 1024, Nout = 1024;
    __shared__ __bf16 sA[128 * GLDA];
    __shared__ __bf16 sB[128 * GLDA];
    const __bf16* A = reinterpret_cast<const __bf16*>(A_);

    int t = threadIdx.x;
    int lane = t & 63, wave = t >> 6;
    int wm = (wave >> 1) * 64, wn = (wave & 1) * 64;
    int quad = lane >> 4, l15 = lane & 15;
    int m0 = blockIdx.y * 128, n0 = blockIdx.x * 128;

    f32x4 acc[4][4];
#pragma unroll
    for (int i = 0; i < 4; i++)
#pragma unroll
        for (int j = 0; j < 4; j++) acc[i][j] = (f32x4)(0.f);

    for (int kt = 0; kt < 16; kt++) {
        int k0 = kt * 64;
#pragma unroll
        for (int cc = 0; cc < 4; cc++) {
            int c = t + cc * 256;
            int row = c >> 3, seg = c & 7;
            bfrag av = *reinterpret_cast<const bfrag*>(A + (size_t)(m0 + row) * K + k0 + seg * 8);
            if (G) {
                bfrag bv2;
#pragma unroll
                for (int j = 0; j < 8; j++) {
                    float fa = (float)av[j];
                    bv2[j] = (__bf16)(fa * G[k0 + seg * 8 + j] + Bv[k0 + seg * 8 + j]);
                }
                av = bv2;
            }
            *reinterpret_cast<bfrag*>(&sA[row * GLDA + seg * 8]) = av;
        }
#pragma unroll
        for (int cc = 0; cc < 4; cc++) {
            int c = t + cc * 256;
            int row = c >> 3, seg = c & 7;
            const float* wp = W + (size_t)(n0 + row) * K + k0 + seg * 8;
            float4 w0 = *reinterpret_cast<const float4*>(wp);
            float4 w1 = *reinterpret_cast<const float4*>(wp + 4);
            bfrag bv2;
            bv2[0] = (__bf16)w0.x; bv2[1] = (__bf16)w0.y; bv2[2] = (__bf16)w0.z; bv2[3] = (__bf16)w0.w;
            bv2[4] = (__bf16)w1.x; bv2[5] = (__bf16)w1.y; bv2[6] = (__bf16)w1.z; bv2[7] = (__bf16)w1.w;
            *reinterpret_cast<bfrag*>(&sB[row * GLDA + seg * 8]) = bv2;
        }
        __syncthreads();
#pragma unroll
        for (int kk = 0; kk < 2; kk++) {
            bfrag af[4], bf[4];
#pragma unroll
            for (int mt = 0; mt < 4; mt++)
                af[mt] = *reinterpret_cast<const bfrag*>(&sA[(wm + mt * 16 + l15) * GLDA + kk * 32 + quad * 8]);
#pragma unroll
            for (int nt = 0; nt < 4; nt++)
                bf[nt] = *reinterpret_cast<const bfrag*>(&sB[(wn + nt * 16 + l15) * GLDA + kk * 32 + quad * 8]);
#pragma unroll
            for (int mt = 0; mt < 4; mt++)
#pragma unroll
                for (int nt = 0; nt < 4; nt++)
                    acc[mt][nt] = __builtin_amdgcn_mfma_f32_16x16x32_bf16(af[mt], bf[nt], acc[mt][nt], 0, 0, 0);
        }
        __syncthreads();
    }
#pragma unroll
    for (int mt = 0; mt < 4; mt++) {
#pragma unroll
        for (int nt = 0; nt < 4; nt++) {
            int col = n0 + wn + nt * 16 + l15;
            float bb = bias ? bias[col] : 0.f;
#pragma unroll
            for (int r = 0; r < 4; r++) {
                int row = m0 + wm + mt * 16 + quad * 4 + r;
                float v = acc[mt][nt][r] + bb;
                if (OUTF32) ((float*)Cout)[(size_t)row * Nout + col] = v;
                else        ((bf16*)Cout)[(size_t)row * Nout + col] = f2bf(v);
            }
        }
    }
}

// ---------------- aggregator pieces -----------------------------------------
__global__ void seg0_kernel(const bf16* __restrict__ t, bf16* __restrict__ th,
                            const float* __restrict__ g, const float* __restrict__ b,
                            const float* __restrict__ m, const float* __restrict__ v) {
    int bc = blockIdx.x;
    int bi = bc / SD_, c = bc % SD_;
    float inv = g[c] * rsqrtf(v[c] + 1e-5f);
    float mm = m[c], bb = b[c];
    const bf16* tp = t + ((size_t)bi * C_ + c) * N_;
    bf16* base = th + (size_t)bi * H_ * C_ * D_;
    for (int n = threadIdx.x; n < N_; n += 256) {
        float y = hswish((bf2f(tp[n]) - mm) * inv + bb);
        base[((n >> 7) * C_ + c) * D_ + (n & 127)] = f2bf(y);
    }
}

template <int KS>
__global__ void dw_kernel(const bf16* __restrict__ t, int cOff,
                          const float* __restrict__ dw, float* __restrict__ outp) {
    int bc = blockIdx.x;
    int bi = bc / SD_, c = bc % SD_;
    const bf16* tp = t + ((size_t)bi * C_ + cOff + c) * N_;
    float w[KS * KS];
#pragma unroll
    for (int q = 0; q < KS * KS; q++) w[q] = dw[c * KS * KS + q];
    float* op = outp + ((size_t)bi * SD_ + c) * N_;
    const int P = KS / 2;
    for (int n = threadIdx.x; n < N_; n += 256) {
        int i = n >> 5, j = n & 31;
        float acc = 0.f;
#pragma unroll
        for (int di = 0; di < KS; di++) {
            int ii = i + di - P;
            if (ii < 0 || ii > 31) continue;
#pragma unroll
            for (int dj = 0; dj < KS; dj++) {
                int jj = j + dj - P;
                if (jj < 0 || jj > 31) continue;
                acc += bf2f(tp[ii * 32 + jj]) * w[di * KS + dj];
            }
        }
        op[n] = acc;
    }
}

template <int MODE>
__global__ void pw_kernel(const float* __restrict__ inp, const float* __restrict__ pw,
                          const float* __restrict__ g, const float* __restrict__ b,
                          const float* __restrict__ m, const float* __restrict__ v,
                          int cOff, bf16* __restrict__ th, float* __restrict__ rawOut) {
    int bo = blockIdx.x;
    int bi = bo / SD_, o = bo % SD_;
    __shared__ float wrow[SD_];
    for (int c = threadIdx.x; c < SD_; c += 256) wrow[c] = pw[o * SD_ + c];
    __syncthreads();
    const float* ip = inp + (size_t)bi * SD_ * N_;
    int t = threadIdx.x;
    float acc[4] = {0.f, 0.f, 0.f, 0.f};
    for (int c = 0; c < SD_; c++) {
        const float* row = ip + (size_t)c * N_;
        float wc = wrow[c];
#pragma unroll
        for (int r = 0; r < 4; r++) acc[r] += row[t + 256 * r] * wc;
    }
    if (MODE == 0) {
        float inv = g[o] * rsqrtf(v[o] + 1e-5f);
        float mm = m[o], bb = b[o];
        bf16* base = th + (size_t)bi * H_ * C_ * D_;
#pragma unroll
        for (int r = 0; r < 4; r++) {
            int n = t + 256 * r;
            float y = hswish((acc[r] - mm) * inv + bb);
            base[((n >> 7) * C_ + cOff + o) * D_ + (n & 127)] = f2bf(y);
        }
    } else {
        float* opr = rawOut + ((size_t)bi * SD_ + o) * N_;
#pragma unroll
        for (int r = 0; r < 4; r++) opr[t + 256 * r] = acc[r];
    }
}

__global__ void gn_stats_kernel(const float* __restrict__ tmp2, float* __restrict__ stats) {
    int bg = blockIdx.x;
    int bi = bg >> 1, grp = bg & 1;
    const float* p = tmp2 + (size_t)bi * SD_ * N_ + (size_t)grp * 39 * N_;
    float s = 0.f, sq = 0.f;
    const int TOT = 39 * N_;
    for (int i = threadIdx.x; i < TOT; i += 256) { float f = p[i]; s += f; sq += f * f; }
    __shared__ float rs[256], rq[256];
    rs[threadIdx.x] = s; rq[threadIdx.x] = sq; __syncthreads();
    for (int o = 128; o > 0; o >>= 1) {
        if (threadIdx.x < o) { rs[threadIdx.x] += rs[threadIdx.x + o]; rq[threadIdx.x] += rq[threadIdx.x + o]; }
        __syncthreads();
    }
    if (threadIdx.x == 0) {
        float mu = rs[0] / (float)TOT;
        float var = rq[0] / (float)TOT - mu * mu;
        stats[bg * 2] = mu;
        stats[bg * 2 + 1] = rsqrtf(var + 1e-5f);
    }
}

__global__ void gn_apply_kernel(const float* __restrict__ tmp2, const float* __restrict__ stats,
                                const float* __restrict__ gg, const float* __restrict__ gb,
                                bf16* __restrict__ th) {
    int bc = blockIdx.x;
    int bi = bc / SD_, c = bc % SD_;
    int grp = c / 39;
    float mu = stats[(bi * 2 + grp) * 2];
    float rstd = stats[(bi * 2 + grp) * 2 + 1];
    float sc = gg[c] * rstd;
    float of = gb[c] - mu * sc;
    const float* p = tmp2 + ((size_t)bi * SD_ + c) * N_;
    bf16* base = th + (size_t)bi * H_ * C_ * D_;
    for (int n = threadIdx.x; n < N_; n += 256) {
        float y = hswish(p[n] * sc + of);
        base[((n >> 7) * C_ + 234 + c) * D_ + (n & 127)] = f2bf(y);
    }
}

// ---- MFMA scores + GELU + scale + softmax, fused ---------------------------
// v2: 512 threads / 8 waves. Wave (wm,wn): wm = 16-row m-tile (4 of them),
// wn = 160-col half. acc[10] (40 VGPR) instead of acc[20] (80) -> VGPR <= 128
// -> 4 waves/SIMD with 2 blocks/CU resident (LDS ~62 KB): occupancy 2x.
// Cross-wave softmax combine (wn pair) via 1 KB LDS.
#define SLDA 136
__global__ __launch_bounds__(512, 4) void attn_mfma_kernel(
        const bf16* __restrict__ qh_, const bf16* __restrict__ kh_,
        float* __restrict__ attnOut) {
    __shared__ __bf16 sQ[64 * SLDA];
    __shared__ __bf16 sK[160 * SLDA];
    __shared__ float smax[64][2];
    __shared__ float ssum[64][2];
    const __bf16* qh = reinterpret_cast<const __bf16*>(qh_);
    const __bf16* kh = reinterpret_cast<const __bf16*>(kh_);

    int strip = blockIdx.x;     // 5 strips of 64 Q-rows
    int bh = blockIdx.y;
    int t = threadIdx.x;
    int lane = t & 63, wave = t >> 6;   // 8 waves
    int quad = lane >> 4, l15 = lane & 15;
    int wm = wave >> 1;         // 0..3: 16-row m-tile
    int wn = wave & 1;          // 0..1: 160-col half assignment

    // stage Q strip: 64 rows x 128 (rows >= 312 clamped; never stored)
#pragma unroll
    for (int cc = 0; cc < 2; cc++) {
        int c = t + cc * 512;
        int row = c >> 4, seg = c & 15;
        int src = strip * 64 + row; if (src > 311) src = 311;
        bfrag v = *reinterpret_cast<const bfrag*>(qh + ((size_t)bh * C_ + src) * D_ + seg * 8);
        *reinterpret_cast<bfrag*>(&sQ[row * SLDA + seg * 8]) = v;
    }

    f32x4 acc[10];
#pragma unroll
    for (int i = 0; i < 10; i++) acc[i] = (f32x4)(0.f);

    bfrag af[4];
    bool afLoaded = false;

    for (int half = 0; half < 2; half++) {
        if (half) __syncthreads();   // all waves done reading sK of prev half
        // stage K rows [half*160, +160); zero-pad c >= 312
        for (int cc = 0; cc < 5; cc++) {
            int c = t + cc * 512;
            int row = c >> 4, seg = c & 15;
            int src = half * 160 + row;
            bfrag v;
            if (src < C_) {
                v = *reinterpret_cast<const bfrag*>(kh + ((size_t)bh * C_ + src) * D_ + seg * 8);
            } else {
#pragma unroll
                for (int j = 0; j < 8; j++) v[j] = (__bf16)0.f;
            }
            *reinterpret_cast<bfrag*>(&sK[row * SLDA + seg * 8]) = v;
        }
        __syncthreads();
        if (!afLoaded) {
#pragma unroll
            for (int ks = 0; ks < 4; ks++)
                af[ks] = *reinterpret_cast<const bfrag*>(&sQ[(wm * 16 + l15) * SLDA + ks * 32 + quad * 8]);
            afLoaded = true;
        }
#pragma unroll
        for (int ks = 0; ks < 4; ks++) {
#pragma unroll
            for (int jj = 0; jj < 5; jj++) {
                int lr = (wn * 5 + jj) * 16 + l15;   // local sK row
                bfrag bf = *reinterpret_cast<const bfrag*>(&sK[lr * SLDA + ks * 32 + quad * 8]);
                acc[half * 5 + jj] = __builtin_amdgcn_mfma_f32_16x16x32_bf16(af[ks], bf, acc[half * 5 + jj], 0, 0, 0);
            }
        }
    }

    // acc[a] holds col-tile gt = (a/5)*10 + wn*5 + (a%5); C-layout row = quad*4+r
    const float scale = 0.08838834764831845f;
    const float inv_sqrt2 = 0.7071067811865475f;
#pragma unroll
    for (int a = 0; a < 10; a++) {
        int gt = (a / 5) * 10 + wn * 5 + (a % 5);
        int col = gt * 16 + l15;
#pragma unroll
        for (int r = 0; r < 4; r++) {
            float v = acc[a][r];
            float ge = 0.5f * v * (1.0f + erff(v * inv_sqrt2));
            float s = ge * scale;
            if (col >= C_) s = -FLT_MAX;
            acc[a][r] = s;
        }
    }
    // per-row max over this wave's 10 tiles, reduce across 16-lane group
    float mx[4];
#pragma unroll
    for (int r = 0; r < 4; r++) {
        float m = -FLT_MAX;
#pragma unroll
        for (int a = 0; a < 10; a++) m = fmaxf(m, acc[a][r]);
        for (int o = 1; o < 16; o <<= 1) m = fmaxf(m, __shfl_xor(m, o));
        mx[r] = m;
    }
    if (l15 == 0) {
#pragma unroll
        for (int r = 0; r < 4; r++) smax[wm * 16 + quad * 4 + r][wn] = mx[r];
    }
    __syncthreads();
    float sm[4];
#pragma unroll
    for (int r = 0; r < 4; r++) {
        int row = wm * 16 + quad * 4 + r;
        float m = fmaxf(smax[row][0], smax[row][1]);
        float s = 0.f;
#pragma unroll
        for (int a = 0; a < 10; a++) {
            float e = __expf(acc[a][r] - m);
            acc[a][r] = e;
            s += e;
        }
        for (int o = 1; o < 16; o <<= 1) s += __shfl_xor(s, o);
        sm[r] = s;
    }
    if (l15 == 0) {
#pragma unroll
        for (int r = 0; r < 4; r++) ssum[wm * 16 + quad * 4 + r][wn] = sm[r];
    }
    __syncthreads();
#pragma unroll
    for (int r = 0; r < 4; r++) {
        int row = wm * 16 + quad * 4 + r;
        float inv = 1.0f / (ssum[row][0] + ssum[row][1]);
        int grow = strip * 64 + row;
        if (grow >= C_) continue;
        float* ao = attnOut + ((size_t)bh * C_ + grow) * C_;
#pragma unroll
        for (int a = 0; a < 10; a++) {
            int gt = (a / 5) * 10 + wn * 5 + (a % 5);
            int col = gt * 16 + l15;
            if (col < C_) ao[col] = acc[a][r] * inv;
        }
    }
}

// ---- MFMA attn @ V -> ctx (scrambled layout) --------------------------------
// v2: P staged fp32->bf16 (k padded to 320 w/ zeros). V staged in frag-order
// LDS in FIVE 64-row k-chunks (16 KB instead of 40 KB -> 37.4 KB total LDS
// -> 4 blocks/CU). Staging loads V along c (8 scalar bf16 at stride D, lanes
// span d so each load is a coalesced 128B row segment) and writes ONE
// contiguous ds_write_b128 per unit -> no 32-way scatter conflicts.
// 4 waves: 2 m-tiles x 2 n-halves.
#define PLDA 328   // 320 + 8 pad: row stride 656B = 164 dw, %32 = 4 banks
__global__ __launch_bounds__(256) void av_mfma_kernel(
        const float* __restrict__ attn, const bf16* __restrict__ vh_,
        bf16* __restrict__ ctx) {
    __shared__ __bf16 sP[32 * PLDA];        // 20992 B
    __shared__ __bf16 sV[2 * 8 * 64 * 8];   // 16384 B  [(ktl,nt,lane) x 8]
    const __bf16* vh = reinterpret_cast<const __bf16*>(vh_);
    int strip = blockIdx.x;                 // 0..9 -> rows strip*32..+31
    int bh = blockIdx.y;
    int t = threadIdx.x;
    int lane = t & 63, wave = t >> 6;
    int quad = lane >> 4, l15 = lane & 15;
    int mt = wave & 1;                      // m-tile (16 rows)
    int nh = wave >> 1;                     // n-half (4 n-tiles of 16 cols)

    // stage P strip: fp32 attn -> bf16, cols padded to 320 with zeros
    for (int g = t; g < 32 * 80; g += 256) {
        int row = g / 80, col4 = g % 80;
        int src = strip * 32 + row; if (src > 311) src = 311;
        __bf16 pk[4];
        if (col4 < 78) {
            float4 a4 = *reinterpret_cast<const float4*>(attn + ((size_t)bh * C_ + src) * C_ + col4 * 4);
            pk[0] = (__bf16)a4.x; pk[1] = (__bf16)a4.y; pk[2] = (__bf16)a4.z; pk[3] = (__bf16)a4.w;
        } else {
            pk[0] = pk[1] = pk[2] = pk[3] = (__bf16)0.f;
        }
        *reinterpret_cast<uint2*>(&sP[row * PLDA + col4 * 4]) = *reinterpret_cast<const uint2*>(pk);
    }

    f32x4 acc[4];
#pragma unroll
    for (int i = 0; i < 4; i++) acc[i] = (f32x4)(0.f);

    // stage V chunk: rows [chunk*64, +64) in frag order.
    // unit = (ktl, quad2, d): 8 bf16 along c -> one b128 write.
    auto stageV = [&](int chunk) {
#pragma unroll
        for (int it = 0; it < 4; it++) {
            int g = t + it * 256;           // 0..1023
            int d = g & 127;
            int oct = g >> 7;               // 0..7
            int ktl = oct >> 2, quad2 = oct & 3;
            int cb = chunk * 64 + ktl * 32 + quad2 * 8;
            const __bf16* vp = vh + ((size_t)bh * C_ + cb) * D_ + d;
            bfrag v;
            if (cb + 7 < C_) {
#pragma unroll
                for (int j = 0; j < 8; j++) v[j] = vp[(size_t)j * D_];
            } else {
#pragma unroll
                for (int j = 0; j < 8; j++) v[j] = (cb + j < C_) ? vp[(size_t)j * D_] : (__bf16)0.f;
            }
            *reinterpret_cast<bfrag*>(&sV[(((ktl * 8 + (d >> 4)) * 64) + quad2 * 16 + (d & 15)) * 8]) = v;
        }
    };

    stageV(0);
    __syncthreads();

    for (int chunk = 0; chunk < 5; chunk++) {
#pragma unroll
        for (int ktl = 0; ktl < 2; ktl++) {
            bfrag a = *reinterpret_cast<const bfrag*>(
                &sP[(mt * 16 + l15) * PLDA + chunk * 64 + ktl * 32 + quad * 8]);
#pragma unroll
            for (int ntl = 0; ntl < 4; ntl++) {
                int ntg = nh * 4 + ntl;
                bfrag b = *reinterpret_cast<const bfrag*>(&sV[(((ktl * 8 + ntg) * 64) + lane) * 8]);
                acc[ntl] = __builtin_amdgcn_mfma_f32_16x16x32_bf16(a, b, acc[ntl], 0, 0, 0);
            }
        }
        if (chunk < 4) {
            __syncthreads();     // all waves done reading sV of this chunk
            stageV(chunk + 1);
            __syncthreads();     // next chunk staged
        }
    }

    // epilogue: ctx[b, h*39 + c/8, (c%8)*128 + d], C-layout row = quad*4+r
    int b = bh >> 3, h = bh & 7;
#pragma unroll
    for (int ntl = 0; ntl < 4; ntl++) {
        int d = nh * 64 + ntl * 16 + l15;
#pragma unroll
        for (int r = 0; r < 4; r++) {
            int c = strip * 32 + mt * 16 + quad * 4 + r;
            if (c < C_) {
                size_t oi = ((size_t)b * C_ + h * 39 + (c >> 3)) * N_ + ((c & 7) << 7) + d;
                ctx[oi] = f2bf(acc[ntl][r]);
            }
        }
    }
}

// ---------------- L2 row norm (fp32 out) -------------------------------------
__global__ void norm_kernel(const float* __restrict__ out3, float* __restrict__ outp) {
    int r = blockIdx.x;
    const float* p = out3 + (size_t)r * N_;
    float sq = 0.f;
    for (int i = threadIdx.x; i < N_; i += 256) { float f = p[i]; sq += f * f; }
    __shared__ float rq[256];
    rq[threadIdx.x] = sq; __syncthreads();
    for (int o = 128; o > 0; o >>= 1) {
        if (threadIdx.x < o) rq[threadIdx.x] += rq[threadIdx.x + o];
        __syncthreads();
    }
    float inv = 1.0f / fmaxf(sqrtf(rq[0]), 1e-12f);
    float* po = outp + (size_t)r * N_;
    for (int i = threadIdx.x; i < N_; i += 256) po[i] = p[i] * inv;
}

// ---------------- host orchestration ----------------------------------------
extern "C" void kernel_launch(void* const* d_in, const int* in_sizes, int n_in,
                              void* d_out, int out_size, void* d_ws, size_t ws_size,
                              hipStream_t stream) {
    const float* x      = (const float*)d_in[0];
    const float* ln_q_g = (const float*)d_in[3];
    const float* ln_q_b = (const float*)d_in[4];
    const float* ln_k_g = (const float*)d_in[5];
    const float* ln_k_b = (const float*)d_in[6];
    const float* ln_v_g = (const float*)d_in[7];
    const float* ln_v_b = (const float*)d_in[8];
    const float* w_q    = (const float*)d_in[9];
    const float* w_k    = (const float*)d_in[10];
    const float* w_v    = (const float*)d_in[11];
    const float* w_proj = (const float*)d_in[12];
    const float* b_proj = (const float*)d_in[13];
    const float* dw0    = (const float*)d_in[14];
    const float* pw0    = (const float*)d_in[15];
    const float* gn_g   = (const float*)d_in[16];
    const float* gn_b   = (const float*)d_in[17];
    const float* dw1    = (const float*)d_in[18];
    const float* pw1    = (const float*)d_in[19];
    const float* dw2    = (const float*)d_in[20];
    const float* pw2    = (const float*)d_in[21];
    const float* bn0_g  = (const float*)d_in[22];
    const float* bn0_b  = (const float*)d_in[23];
    const float* bn0_m  = (const float*)d_in[24];
    const float* bn0_v  = (const float*)d_in[25];
    const float* bn1_g  = (const float*)d_in[26];
    const float* bn1_b  = (const float*)d_in[27];
    const float* bn1_m  = (const float*)d_in[28];
    const float* bn1_v  = (const float*)d_in[29];
    const float* bn2_g  = (const float*)d_in[30];
    const float* bn2_b  = (const float*)d_in[31];
    const float* bn2_m  = (const float*)d_in[32];
    const float* bn2_v  = (const float*)d_in[33];

    char* ws = (char*)d_ws;
    size_t off = 0;
    auto alloc = [&](size_t bytes) {
        void* p = ws + off;
        off = (off + bytes + 255) & ~(size_t)255;
        return p;
    };
    const size_t BF_BYTES = (size_t)BC_ * N_ * sizeof(bf16);
    bf16*  xn   = (bf16*)alloc(BF_BYTES);
    bf16*  qb   = (bf16*)alloc(BF_BYTES);
    bf16*  kb   = (bf16*)alloc(BF_BYTES);
    bf16*  vb   = (bf16*)alloc(BF_BYTES);
    float* tmp1 = (float*)alloc((size_t)B_ * SD_ * N_ * sizeof(float));
    float* tmp2 = (float*)alloc((size_t)B_ * SD_ * N_ * sizeof(float));
    float* gnst = (float*)alloc(512);
    bf16* qh  = xn;
    bf16* kh  = qb;
    bf16* vh  = kb;
    bf16* ctx = vb;
    float* out3 = (float*)xn;   // aliases xn+qb (dead after attn/av)

    float* out_main = (float*)d_out;
    float* attn_out = out_main + (size_t)BC_ * N_;

    dim3 gemm_grid(8, 78);

    hipLaunchKernelGGL(ln_kernel, dim3(BC_), dim3(256), 0, stream, x, xn);
    hipLaunchKernelGGL((mfma_gemm_kernel<false>), gemm_grid, dim3(256), 0, stream,
                       xn, ln_q_g, ln_q_b, w_q, (const float*)nullptr, (void*)qb);
    hipLaunchKernelGGL((mfma_gemm_kernel<false>), gemm_grid, dim3(256), 0, stream,
                       xn, ln_k_g, ln_k_b, w_k, (const float*)nullptr, (void*)kb);
    hipLaunchKernelGGL((mfma_gemm_kernel<false>), gemm_grid, dim3(256), 0, stream,
                       xn, ln_v_g, ln_v_b, w_v, (const float*)nullptr, (void*)vb);

    const bf16* tins[3] = {qb, kb, vb};
    bf16* thouts[3] = {qh, kh, vh};
    for (int i = 0; i < 3; i++) {
        const bf16* t = tins[i];
        bf16* th = thouts[i];
        dim3 g2496(B_ * SD_);
        hipLaunchKernelGGL(seg0_kernel, g2496, dim3(256), 0, stream,
                           t, th, bn0_g, bn0_b, bn0_m, bn0_v);
        hipLaunchKernelGGL((dw_kernel<3>), g2496, dim3(256), 0, stream, t, SD_, dw1, tmp1);
        hipLaunchKernelGGL((pw_kernel<0>), g2496, dim3(256), 0, stream,
                           tmp1, pw1, bn1_g, bn1_b, bn1_m, bn1_v, SD_, th, (float*)nullptr);
        hipLaunchKernelGGL((dw_kernel<5>), g2496, dim3(256), 0, stream, t, 2 * SD_, dw2, tmp1);
        hipLaunchKernelGGL((pw_kernel<0>), g2496, dim3(256), 0, stream,
                           tmp1, pw2, bn2_g, bn2_b, bn2_m, bn2_v, 2 * SD_, th, (float*)nullptr);
        hipLaunchKernelGGL((dw_kernel<3>), g2496, dim3(256), 0, stream, t, 3 * SD_, dw0, tmp1);
        hipLaunchKernelGGL((pw_kernel<1>), g2496, dim3(256), 0, stream,
                           tmp1, pw0, (const float*)nullptr, (const float*)nullptr,
                           (const float*)nullptr, (const float*)nullptr, 0, (bf16*)nullptr, tmp2);
        hipLaunchKernelGGL(gn_stats_kernel, dim3(B_ * 2), dim3(256), 0, stream, tmp2, gnst);
        hipLaunchKernelGGL(gn_apply_kernel, g2496, dim3(256), 0, stream, tmp2, gnst, gn_g, gn_b, th);
    }

    hipLaunchKernelGGL(attn_mfma_kernel, dim3(5, BH_), dim3(512), 0, stream, qh, kh, attn_out);
    hipLaunchKernelGGL(av_mfma_kernel, dim3(10, BH_), dim3(256), 0, stream, attn_out, vh, ctx);
    hipLaunchKernelGGL((mfma_gemm_kernel<true>), gemm_grid, dim3(256), 0, stream,
                       ctx, (const float*)nullptr, (const float*)nullptr, w_proj, b_proj,
                       (void*)out3);
    hipLaunchKernelGGL(norm_kernel, dim3(BC_), dim3(256), 0, stream, out3, out_main);
}

// Round 4
// 1138.481 us; speedup vs baseline: 1.2673x; 1.1784x over previous
//
#include <hip/hip_runtime.h>
#include <hip/hip_bf16.h>
#include <float.h>

typedef __hip_bfloat16 bf16;
typedef __attribute__((ext_vector_type(8))) __bf16 bfrag;   // MFMA A/B operand (4 VGPRs)
typedef __attribute__((ext_vector_type(4))) float f32x4;    // MFMA C/D operand

#define B_ 32
#define C_ 312
#define N_ 1024
#define H_ 8
#define D_ 128
#define SD_ 78
#define BC_ (B_ * C_)      // 9984
#define BH_ (B_ * H_)      // 256

__device__ __forceinline__ float bf2f(bf16 x) { return __bfloat162float(x); }
__device__ __forceinline__ bf16 f2bf(float x) { return __float2bfloat16(x); }
__device__ __forceinline__ float hswish(float x) {
    return x * fminf(fmaxf(x + 3.0f, 0.0f), 6.0f) * (1.0f / 6.0f);
}

// ---------------- LayerNorm (stats only; affine folded into W) --------------
__global__ void ln_kernel(const float* __restrict__ x, bf16* __restrict__ xn) {
    int r = blockIdx.x;
    int t = threadIdx.x;
    const float* xr = x + (size_t)r * N_;
    float s = 0.f, sq = 0.f;
    for (int i = t; i < N_; i += 256) { float f = xr[i]; s += f; sq += f * f; }
    __shared__ float rs[256], rq[256];
    rs[t] = s; rq[t] = sq; __syncthreads();
    for (int o = 128; o > 0; o >>= 1) {
        if (t < o) { rs[t] += rs[t + o]; rq[t] += rq[t + o]; }
        __syncthreads();
    }
    float mu = rs[0] * (1.0f / N_);
    float var = rq[0] * (1.0f / N_) - mu * mu;
    float rstd = rsqrtf(var + 1e-5f);
    bf16* xo = xn + (size_t)r * N_;
    for (int i = t; i < N_; i += 256) xo[i] = f2bf((xr[i] - mu) * rstd);
}

// ---- W preconvert: fold LN gamma into W (bf16), beta into bias row ---------
// rows 0..1023: wq*gq ; 1024..2047: wk*gk ; 2048..3071: wv*gv ; 3072..4095: w_proj plain
__global__ void wcvt_kernel(const float* __restrict__ wq, const float* __restrict__ wk,
                            const float* __restrict__ wv, const float* __restrict__ wp,
                            const float* __restrict__ gq, const float* __restrict__ bq,
                            const float* __restrict__ gk, const float* __restrict__ bk,
                            const float* __restrict__ gv, const float* __restrict__ bv_,
                            bf16* __restrict__ wqkv, float* __restrict__ bias3,
                            bf16* __restrict__ wpb) {
    int n = blockIdx.x;          // 0..4095
    int t = threadIdx.x;         // 256
    int k4 = t * 4;
    const float* src; const float* G = nullptr; const float* Bv = nullptr;
    if (n < 1024)      { src = wq + (size_t)n * N_;          G = gq; Bv = bq; }
    else if (n < 2048) { src = wk + (size_t)(n - 1024) * N_; G = gk; Bv = bk; }
    else if (n < 3072) { src = wv + (size_t)(n - 2048) * N_; G = gv; Bv = bv_; }
    else               { src = wp + (size_t)(n - 3072) * N_; }
    float4 w4 = *reinterpret_cast<const float4*>(src + k4);
    if (G) {
        __bf16 o[4] = { (__bf16)(w4.x * G[k4]),     (__bf16)(w4.y * G[k4 + 1]),
                        (__bf16)(w4.z * G[k4 + 2]), (__bf16)(w4.w * G[k4 + 3]) };
        *reinterpret_cast<uint2*>(wqkv + (size_t)n * N_ + k4) = *reinterpret_cast<const uint2*>(o);
        float s = w4.x * Bv[k4] + w4.y * Bv[k4 + 1] + w4.z * Bv[k4 + 2] + w4.w * Bv[k4 + 3];
        __shared__ float rs[256];
        rs[t] = s; __syncthreads();
        for (int o2 = 128; o2 > 0; o2 >>= 1) {
            if (t < o2) rs[t] += rs[t + o2];
            __syncthreads();
        }
        if (t == 0) bias3[n] = rs[0];
    } else {
        __bf16 o[4] = { (__bf16)w4.x, (__bf16)w4.y, (__bf16)w4.z, (__bf16)w4.w };
        *reinterpret_cast<uint2*>(wpb + (size_t)(n - 3072) * N_ + k4) = *reinterpret_cast<const uint2*>(o);
    }
}

// ---------------- MFMA GEMM (bf16 W): C[M, n-tiles] = A @ W^T + bias --------
// grid.x = total 128-col n-tiles across up to 3 output buffers (8 tiles each).
// which = blockIdx.x/8 selects O0/O1/O2; col within buffer = (blockIdx.x%8)*128.
#define GLDA 72   // LDS row stride (bf16 elems): 64 + 8 pad
template <bool OUTF32>
__global__ __launch_bounds__(256) void mfma_gemm_bw(
        const bf16* __restrict__ A_,
        const bf16* __restrict__ Wb,
        const float* __restrict__ bias,
        void* __restrict__ O0, void* __restrict__ O1, void* __restrict__ O2) {
    const int K = 1024, Nout = 1024;
    __shared__ __bf16 sA[128 * GLDA];
    __shared__ __bf16 sB[128 * GLDA];
    const __bf16* A = reinterpret_cast<const __bf16*>(A_);
    const __bf16* W = reinterpret_cast<const __bf16*>(Wb);

    int t = threadIdx.x;
    int lane = t & 63, wave = t >> 6;
    int wm = (wave >> 1) * 64, wn = (wave & 1) * 64;
    int quad = lane >> 4, l15 = lane & 15;
    int m0 = blockIdx.y * 128;
    int w0 = blockIdx.x * 128;          // global W row base
    int which = blockIdx.x >> 3;
    int n0 = (blockIdx.x & 7) * 128;    // col within selected output buffer

    f32x4 acc[4][4];
#pragma unroll
    for (int i = 0; i < 4; i++)
#pragma unroll
        for (int j = 0; j < 4; j++) acc[i][j] = (f32x4)(0.f);

    for (int kt = 0; kt < 16; kt++) {
        int k0 = kt * 64;
#pragma unroll
        for (int cc = 0; cc < 4; cc++) {
            int c = t + cc * 256;
            int row = c >> 3, seg = c & 7;
            *reinterpret_cast<bfrag*>(&sA[row * GLDA + seg * 8]) =
                *reinterpret_cast<const bfrag*>(A + (size_t)(m0 + row) * K + k0 + seg * 8);
            *reinterpret_cast<bfrag*>(&sB[row * GLDA + seg * 8]) =
                *reinterpret_cast<const bfrag*>(W + (size_t)(w0 + row) * K + k0 + seg * 8);
        }
        __syncthreads();
#pragma unroll
        for (int kk = 0; kk < 2; kk++) {
            bfrag af[4], bf[4];
#pragma unroll
            for (int mt = 0; mt < 4; mt++)
                af[mt] = *reinterpret_cast<const bfrag*>(&sA[(wm + mt * 16 + l15) * GLDA + kk * 32 + quad * 8]);
#pragma unroll
            for (int nt = 0; nt < 4; nt++)
                bf[nt] = *reinterpret_cast<const bfrag*>(&sB[(wn + nt * 16 + l15) * GLDA + kk * 32 + quad * 8]);
#pragma unroll
            for (int mt = 0; mt < 4; mt++)
#pragma unroll
                for (int nt = 0; nt < 4; nt++)
                    acc[mt][nt] = __builtin_amdgcn_mfma_f32_16x16x32_bf16(af[mt], bf[nt], acc[mt][nt], 0, 0, 0);
        }
        __syncthreads();
    }
    void* Cout = which == 0 ? O0 : (which == 1 ? O1 : O2);
#pragma unroll
    for (int mt = 0; mt < 4; mt++) {
#pragma unroll
        for (int nt = 0; nt < 4; nt++) {
            int cloc = wn + nt * 16 + l15;
            float bb = bias ? bias[w0 + cloc] : 0.f;
            int col = n0 + cloc;
#pragma unroll
            for (int r = 0; r < 4; r++) {
                int row = m0 + wm + mt * 16 + quad * 4 + r;
                float v = acc[mt][nt][r] + bb;
                if (OUTF32) ((float*)Cout)[(size_t)row * Nout + col] = v;
                else        ((bf16*)Cout)[(size_t)row * Nout + col] = f2bf(v);
            }
        }
    }
}

// ---------------- aggregator pieces -----------------------------------------
__global__ void seg0_kernel(const bf16* __restrict__ t, bf16* __restrict__ th,
                            const float* __restrict__ g, const float* __restrict__ b,
                            const float* __restrict__ m, const float* __restrict__ v) {
    int bc = blockIdx.x;
    int bi = bc / SD_, c = bc % SD_;
    float inv = g[c] * rsqrtf(v[c] + 1e-5f);
    float mm = m[c], bb = b[c];
    const bf16* tp = t + ((size_t)bi * C_ + c) * N_;
    bf16* base = th + (size_t)bi * H_ * C_ * D_;
    for (int n = threadIdx.x; n < N_; n += 256) {
        float y = hswish((bf2f(tp[n]) - mm) * inv + bb);
        base[((n >> 7) * C_ + c) * D_ + (n & 127)] = f2bf(y);
    }
}

template <int KS>
__global__ void dw_kernel(const bf16* __restrict__ t, int cOff,
                          const float* __restrict__ dw, float* __restrict__ outp) {
    int bc = blockIdx.x;
    int bi = bc / SD_, c = bc % SD_;
    const bf16* tp = t + ((size_t)bi * C_ + cOff + c) * N_;
    float w[KS * KS];
#pragma unroll
    for (int q = 0; q < KS * KS; q++) w[q] = dw[c * KS * KS + q];
    float* op = outp + ((size_t)bi * SD_ + c) * N_;
    const int P = KS / 2;
    for (int n = threadIdx.x; n < N_; n += 256) {
        int i = n >> 5, j = n & 31;
        float acc = 0.f;
#pragma unroll
        for (int di = 0; di < KS; di++) {
            int ii = i + di - P;
            if (ii < 0 || ii > 31) continue;
#pragma unroll
            for (int dj = 0; dj < KS; dj++) {
                int jj = j + dj - P;
                if (jj < 0 || jj > 31) continue;
                acc += bf2f(tp[ii * 32 + jj]) * w[di * KS + dj];
            }
        }
        op[n] = acc;
    }
}

template <int MODE>
__global__ void pw_kernel(const float* __restrict__ inp, const float* __restrict__ pw,
                          const float* __restrict__ g, const float* __restrict__ b,
                          const float* __restrict__ m, const float* __restrict__ v,
                          int cOff, bf16* __restrict__ th, float* __restrict__ rawOut) {
    int bo = blockIdx.x;
    int bi = bo / SD_, o = bo % SD_;
    __shared__ float wrow[SD_];
    for (int c = threadIdx.x; c < SD_; c += 256) wrow[c] = pw[o * SD_ + c];
    __syncthreads();
    const float* ip = inp + (size_t)bi * SD_ * N_;
    int t = threadIdx.x;
    float acc[4] = {0.f, 0.f, 0.f, 0.f};
    for (int c = 0; c < SD_; c++) {
        const float* row = ip + (size_t)c * N_;
        float wc = wrow[c];
#pragma unroll
        for (int r = 0; r < 4; r++) acc[r] += row[t + 256 * r] * wc;
    }
    if (MODE == 0) {
        float inv = g[o] * rsqrtf(v[o] + 1e-5f);
        float mm = m[o], bb = b[o];
        bf16* base = th + (size_t)bi * H_ * C_ * D_;
#pragma unroll
        for (int r = 0; r < 4; r++) {
            int n = t + 256 * r;
            float y = hswish((acc[r] - mm) * inv + bb);
            base[((n >> 7) * C_ + cOff + o) * D_ + (n & 127)] = f2bf(y);
        }
    } else {
        float* opr = rawOut + ((size_t)bi * SD_ + o) * N_;
#pragma unroll
        for (int r = 0; r < 4; r++) opr[t + 256 * r] = acc[r];
    }
}

__global__ void gn_stats_kernel(const float* __restrict__ tmp2, float* __restrict__ stats) {
    int bg = blockIdx.x;
    int bi = bg >> 1, grp = bg & 1;
    const float* p = tmp2 + (size_t)bi * SD_ * N_ + (size_t)grp * 39 * N_;
    float s = 0.f, sq = 0.f;
    const int TOT = 39 * N_;
    for (int i = threadIdx.x; i < TOT; i += 256) { float f = p[i]; s += f; sq += f * f; }
    __shared__ float rs[256], rq[256];
    rs[threadIdx.x] = s; rq[threadIdx.x] = sq; __syncthreads();
    for (int o = 128; o > 0; o >>= 1) {
        if (threadIdx.x < o) { rs[threadIdx.x] += rs[threadIdx.x + o]; rq[threadIdx.x] += rq[threadIdx.x + o]; }
        __syncthreads();
    }
    if (threadIdx.x == 0) {
        float mu = rs[0] / (float)TOT;
        float var = rq[0] / (float)TOT - mu * mu;
        stats[bg * 2] = mu;
        stats[bg * 2 + 1] = rsqrtf(var + 1e-5f);
    }
}

__global__ void gn_apply_kernel(const float* __restrict__ tmp2, const float* __restrict__ stats,
                                const float* __restrict__ gg, const float* __restrict__ gb,
                                bf16* __restrict__ th) {
    int bc = blockIdx.x;
    int bi = bc / SD_, c = bc % SD_;
    int grp = c / 39;
    float mu = stats[(bi * 2 + grp) * 2];
    float rstd = stats[(bi * 2 + grp) * 2 + 1];
    float sc = gg[c] * rstd;
    float of = gb[c] - mu * sc;
    const float* p = tmp2 + ((size_t)bi * SD_ + c) * N_;
    bf16* base = th + (size_t)bi * H_ * C_ * D_;
    for (int n = threadIdx.x; n < N_; n += 256) {
        float y = hswish(p[n] * sc + of);
        base[((n >> 7) * C_ + 234 + c) * D_ + (n & 127)] = f2bf(y);
    }
}

// ---- MFMA scores + GELU + scale + softmax, fused ---------------------------
// 512 threads / 8 waves. Wave (wm,wn): wm = 16-row m-tile (4), wn = 160-col half.
#define SLDA 136
__global__ __launch_bounds__(512, 4) void attn_mfma_kernel(
        const bf16* __restrict__ qh_, const bf16* __restrict__ kh_,
        float* __restrict__ attnOut) {
    __shared__ __bf16 sQ[64 * SLDA];
    __shared__ __bf16 sK[160 * SLDA];
    __shared__ float smax[64][2];
    __shared__ float ssum[64][2];
    const __bf16* qh = reinterpret_cast<const __bf16*>(qh_);
    const __bf16* kh = reinterpret_cast<const __bf16*>(kh_);

    int strip = blockIdx.x;     // 5 strips of 64 Q-rows
    int bh = blockIdx.y;
    int t = threadIdx.x;
    int lane = t & 63, wave = t >> 6;   // 8 waves
    int quad = lane >> 4, l15 = lane & 15;
    int wm = wave >> 1;         // 0..3: 16-row m-tile
    int wn = wave & 1;          // 0..1: 160-col half assignment

#pragma unroll
    for (int cc = 0; cc < 2; cc++) {
        int c = t + cc * 512;
        int row = c >> 4, seg = c & 15;
        int src = strip * 64 + row; if (src > 311) src = 311;
        bfrag v = *reinterpret_cast<const bfrag*>(qh + ((size_t)bh * C_ + src) * D_ + seg * 8);
        *reinterpret_cast<bfrag*>(&sQ[row * SLDA + seg * 8]) = v;
    }

    f32x4 acc[10];
#pragma unroll
    for (int i = 0; i < 10; i++) acc[i] = (f32x4)(0.f);

    bfrag af[4];
    bool afLoaded = false;

    for (int half = 0; half < 2; half++) {
        if (half) __syncthreads();
        for (int cc = 0; cc < 5; cc++) {
            int c = t + cc * 512;
            int row = c >> 4, seg = c & 15;
            int src = half * 160 + row;
            bfrag v;
            if (src < C_) {
                v = *reinterpret_cast<const bfrag*>(kh + ((size_t)bh * C_ + src) * D_ + seg * 8);
            } else {
#pragma unroll
                for (int j = 0; j < 8; j++) v[j] = (__bf16)0.f;
            }
            *reinterpret_cast<bfrag*>(&sK[row * SLDA + seg * 8]) = v;
        }
        __syncthreads();
        if (!afLoaded) {
#pragma unroll
            for (int ks = 0; ks < 4; ks++)
                af[ks] = *reinterpret_cast<const bfrag*>(&sQ[(wm * 16 + l15) * SLDA + ks * 32 + quad * 8]);
            afLoaded = true;
        }
#pragma unroll
        for (int ks = 0; ks < 4; ks++) {
#pragma unroll
            for (int jj = 0; jj < 5; jj++) {
                int lr = (wn * 5 + jj) * 16 + l15;
                bfrag bf = *reinterpret_cast<const bfrag*>(&sK[lr * SLDA + ks * 32 + quad * 8]);
                acc[half * 5 + jj] = __builtin_amdgcn_mfma_f32_16x16x32_bf16(af[ks], bf, acc[half * 5 + jj], 0, 0, 0);
            }
        }
    }

    const float scale = 0.08838834764831845f;
    const float inv_sqrt2 = 0.7071067811865475f;
#pragma unroll
    for (int a = 0; a < 10; a++) {
        int gt = (a / 5) * 10 + wn * 5 + (a % 5);
        int col = gt * 16 + l15;
#pragma unroll
        for (int r = 0; r < 4; r++) {
            float v = acc[a][r];
            float ge = 0.5f * v * (1.0f + erff(v * inv_sqrt2));
            float s = ge * scale;
            if (col >= C_) s = -FLT_MAX;
            acc[a][r] = s;
        }
    }
    float mx[4];
#pragma unroll
    for (int r = 0; r < 4; r++) {
        float m = -FLT_MAX;
#pragma unroll
        for (int a = 0; a < 10; a++) m = fmaxf(m, acc[a][r]);
        for (int o = 1; o < 16; o <<= 1) m = fmaxf(m, __shfl_xor(m, o));
        mx[r] = m;
    }
    if (l15 == 0) {
#pragma unroll
        for (int r = 0; r < 4; r++) smax[wm * 16 + quad * 4 + r][wn] = mx[r];
    }
    __syncthreads();
    float sm[4];
#pragma unroll
    for (int r = 0; r < 4; r++) {
        int row = wm * 16 + quad * 4 + r;
        float m = fmaxf(smax[row][0], smax[row][1]);
        float s = 0.f;
#pragma unroll
        for (int a = 0; a < 10; a++) {
            float e = __expf(acc[a][r] - m);
            acc[a][r] = e;
            s += e;
        }
        for (int o = 1; o < 16; o <<= 1) s += __shfl_xor(s, o);
        sm[r] = s;
    }
    if (l15 == 0) {
#pragma unroll
        for (int r = 0; r < 4; r++) ssum[wm * 16 + quad * 4 + r][wn] = sm[r];
    }
    __syncthreads();
#pragma unroll
    for (int r = 0; r < 4; r++) {
        int row = wm * 16 + quad * 4 + r;
        float inv = 1.0f / (ssum[row][0] + ssum[row][1]);
        int grow = strip * 64 + row;
        if (grow >= C_) continue;
        float* ao = attnOut + ((size_t)bh * C_ + grow) * C_;
#pragma unroll
        for (int a = 0; a < 10; a++) {
            int gt = (a / 5) * 10 + wn * 5 + (a % 5);
            int col = gt * 16 + l15;
            if (col < C_) ao[col] = acc[a][r] * inv;
        }
    }
}

// ---- MFMA attn @ V -> ctx (scrambled layout) --------------------------------
#define PLDA 328   // 320 + 8 pad
__global__ __launch_bounds__(256) void av_mfma_kernel(
        const float* __restrict__ attn, const bf16* __restrict__ vh_,
        bf16* __restrict__ ctx) {
    __shared__ __bf16 sP[32 * PLDA];        // 20992 B
    __shared__ __bf16 sV[2 * 8 * 64 * 8];   // 16384 B  [(ktl,nt,lane) x 8]
    const __bf16* vh = reinterpret_cast<const __bf16*>(vh_);
    int strip = blockIdx.x;                 // 0..9 -> rows strip*32..+31
    int bh = blockIdx.y;
    int t = threadIdx.x;
    int lane = t & 63, wave = t >> 6;
    int quad = lane >> 4, l15 = lane & 15;
    int mt = wave & 1;
    int nh = wave >> 1;

    for (int g = t; g < 32 * 80; g += 256) {
        int row = g / 80, col4 = g % 80;
        int src = strip * 32 + row; if (src > 311) src = 311;
        __bf16 pk[4];
        if (col4 < 78) {
            float4 a4 = *reinterpret_cast<const float4*>(attn + ((size_t)bh * C_ + src) * C_ + col4 * 4);
            pk[0] = (__bf16)a4.x; pk[1] = (__bf16)a4.y; pk[2] = (__bf16)a4.z; pk[3] = (__bf16)a4.w;
        } else {
            pk[0] = pk[1] = pk[2] = pk[3] = (__bf16)0.f;
        }
        *reinterpret_cast<uint2*>(&sP[row * PLDA + col4 * 4]) = *reinterpret_cast<const uint2*>(pk);
    }

    f32x4 acc[4];
#pragma unroll
    for (int i = 0; i < 4; i++) acc[i] = (f32x4)(0.f);

    auto stageV = [&](int chunk) {
#pragma unroll
        for (int it = 0; it < 4; it++) {
            int g = t + it * 256;
            int d = g & 127;
            int oct = g >> 7;
            int ktl = oct >> 2, quad2 = oct & 3;
            int cb = chunk * 64 + ktl * 32 + quad2 * 8;
            const __bf16* vp = vh + ((size_t)bh * C_ + cb) * D_ + d;
            bfrag v;
            if (cb + 7 < C_) {
#pragma unroll
                for (int j = 0; j < 8; j++) v[j] = vp[(size_t)j * D_];
            } else {
#pragma unroll
                for (int j = 0; j < 8; j++) v[j] = (cb + j < C_) ? vp[(size_t)j * D_] : (__bf16)0.f;
            }
            *reinterpret_cast<bfrag*>(&sV[(((ktl * 8 + (d >> 4)) * 64) + quad2 * 16 + (d & 15)) * 8]) = v;
        }
    };

    stageV(0);
    __syncthreads();

    for (int chunk = 0; chunk < 5; chunk++) {
#pragma unroll
        for (int ktl = 0; ktl < 2; ktl++) {
            bfrag a = *reinterpret_cast<const bfrag*>(
                &sP[(mt * 16 + l15) * PLDA + chunk * 64 + ktl * 32 + quad * 8]);
#pragma unroll
            for (int ntl = 0; ntl < 4; ntl++) {
                int ntg = nh * 4 + ntl;
                bfrag b = *reinterpret_cast<const bfrag*>(&sV[(((ktl * 8 + ntg) * 64) + lane) * 8]);
                acc[ntl] = __builtin_amdgcn_mfma_f32_16x16x32_bf16(a, b, acc[ntl], 0, 0, 0);
            }
        }
        if (chunk < 4) {
            __syncthreads();
            stageV(chunk + 1);
            __syncthreads();
        }
    }

    int b = bh >> 3, h = bh & 7;
#pragma unroll
    for (int ntl = 0; ntl < 4; ntl++) {
        int d = nh * 64 + ntl * 16 + l15;
#pragma unroll
        for (int r = 0; r < 4; r++) {
            int c = strip * 32 + mt * 16 + quad * 4 + r;
            if (c < C_) {
                size_t oi = ((size_t)b * C_ + h * 39 + (c >> 3)) * N_ + ((c & 7) << 7) + d;
                ctx[oi] = f2bf(acc[ntl][r]);
            }
        }
    }
}

// ---------------- L2 row norm (fp32 out) -------------------------------------
__global__ void norm_kernel(const float* __restrict__ out3, float* __restrict__ outp) {
    int r = blockIdx.x;
    const float* p = out3 + (size_t)r * N_;
    float sq = 0.f;
    for (int i = threadIdx.x; i < N_; i += 256) { float f = p[i]; sq += f * f; }
    __shared__ float rq[256];
    rq[threadIdx.x] = sq; __syncthreads();
    for (int o = 128; o > 0; o >>= 1) {
        if (threadIdx.x < o) rq[threadIdx.x] += rq[threadIdx.x + o];
        __syncthreads();
    }
    float inv = 1.0f / fmaxf(sqrtf(rq[0]), 1e-12f);
    float* po = outp + (size_t)r * N_;
    for (int i = threadIdx.x; i < N_; i += 256) po[i] = p[i] * inv;
}

// ---------------- host orchestration ----------------------------------------
extern "C" void kernel_launch(void* const* d_in, const int* in_sizes, int n_in,
                              void* d_out, int out_size, void* d_ws, size_t ws_size,
                              hipStream_t stream) {
    const float* x      = (const float*)d_in[0];
    const float* ln_q_g = (const float*)d_in[3];
    const float* ln_q_b = (const float*)d_in[4];
    const float* ln_k_g = (const float*)d_in[5];
    const float* ln_k_b = (const float*)d_in[6];
    const float* ln_v_g = (const float*)d_in[7];
    const float* ln_v_b = (const float*)d_in[8];
    const float* w_q    = (const float*)d_in[9];
    const float* w_k    = (const float*)d_in[10];
    const float* w_v    = (const float*)d_in[11];
    const float* w_proj = (const float*)d_in[12];
    const float* b_proj = (const float*)d_in[13];
    const float* dw0    = (const float*)d_in[14];
    const float* pw0    = (const float*)d_in[15];
    const float* gn_g   = (const float*)d_in[16];
    const float* gn_b   = (const float*)d_in[17];
    const float* dw1    = (const float*)d_in[18];
    const float* pw1    = (const float*)d_in[19];
    const float* dw2    = (const float*)d_in[20];
    const float* pw2    = (const float*)d_in[21];
    const float* bn0_g  = (const float*)d_in[22];
    const float* bn0_b  = (const float*)d_in[23];
    const float* bn0_m  = (const float*)d_in[24];
    const float* bn0_v  = (const float*)d_in[25];
    const float* bn1_g  = (const float*)d_in[26];
    const float* bn1_b  = (const float*)d_in[27];
    const float* bn1_m  = (const float*)d_in[28];
    const float* bn1_v  = (const float*)d_in[29];
    const float* bn2_g  = (const float*)d_in[30];
    const float* bn2_b  = (const float*)d_in[31];
    const float* bn2_m  = (const float*)d_in[32];
    const float* bn2_v  = (const float*)d_in[33];

    char* ws = (char*)d_ws;
    size_t off = 0;
    auto alloc = [&](size_t bytes) {
        void* p = ws + off;
        off = (off + bytes + 255) & ~(size_t)255;
        return p;
    };
    const size_t BF_BYTES = (size_t)BC_ * N_ * sizeof(bf16);
    bf16*  xn   = (bf16*)alloc(BF_BYTES);
    bf16*  qb   = (bf16*)alloc(BF_BYTES);
    bf16*  kb   = (bf16*)alloc(BF_BYTES);
    bf16*  vb   = (bf16*)alloc(BF_BYTES);
    float* tmp1 = (float*)alloc((size_t)B_ * SD_ * N_ * sizeof(float));
    float* tmp2 = (float*)alloc((size_t)B_ * SD_ * N_ * sizeof(float));
    float* gnst = (float*)alloc(512);
    bf16*  wqkv = (bf16*)alloc((size_t)3 * N_ * N_ * sizeof(bf16));   // 6 MB
    float* bias3 = (float*)alloc((size_t)3 * N_ * sizeof(float));
    bf16*  wpb  = (bf16*)alloc((size_t)N_ * N_ * sizeof(bf16));       // 2 MB
    bf16* qh  = xn;
    bf16* kh  = qb;
    bf16* vh  = kb;
    bf16* ctx = vb;
    float* out3 = (float*)xn;   // aliases xn+qb (dead after attn/av)

    float* out_main = (float*)d_out;
    float* attn_out = out_main + (size_t)BC_ * N_;

    hipLaunchKernelGGL(wcvt_kernel, dim3(4096), dim3(256), 0, stream,
                       w_q, w_k, w_v, w_proj,
                       ln_q_g, ln_q_b, ln_k_g, ln_k_b, ln_v_g, ln_v_b,
                       wqkv, bias3, wpb);
    hipLaunchKernelGGL(ln_kernel, dim3(BC_), dim3(256), 0, stream, x, xn);
    hipLaunchKernelGGL((mfma_gemm_bw<false>), dim3(24, 78), dim3(256), 0, stream,
                       xn, wqkv, bias3, (void*)qb, (void*)kb, (void*)vb);

    const bf16* tins[3] = {qb, kb, vb};
    bf16* thouts[3] = {qh, kh, vh};
    for (int i = 0; i < 3; i++) {
        const bf16* t = tins[i];
        bf16* th = thouts[i];
        dim3 g2496(B_ * SD_);
        hipLaunchKernelGGL(seg0_kernel, g2496, dim3(256), 0, stream,
                           t, th, bn0_g, bn0_b, bn0_m, bn0_v);
        hipLaunchKernelGGL((dw_kernel<3>), g2496, dim3(256), 0, stream, t, SD_, dw1, tmp1);
        hipLaunchKernelGGL((pw_kernel<0>), g2496, dim3(256), 0, stream,
                           tmp1, pw1, bn1_g, bn1_b, bn1_m, bn1_v, SD_, th, (float*)nullptr);
        hipLaunchKernelGGL((dw_kernel<5>), g2496, dim3(256), 0, stream, t, 2 * SD_, dw2, tmp1);
        hipLaunchKernelGGL((pw_kernel<0>), g2496, dim3(256), 0, stream,
                           tmp1, pw2, bn2_g, bn2_b, bn2_m, bn2_v, 2 * SD_, th, (float*)nullptr);
        hipLaunchKernelGGL((dw_kernel<3>), g2496, dim3(256), 0, stream, t, 3 * SD_, dw0, tmp1);
        hipLaunchKernelGGL((pw_kernel<1>), g2496, dim3(256), 0, stream,
                           tmp1, pw0, (const float*)nullptr, (const float*)nullptr,
                           (const float*)nullptr, (const float*)nullptr, 0, (bf16*)nullptr, tmp2);
        hipLaunchKernelGGL(gn_stats_kernel, dim3(B_ * 2), dim3(256), 0, stream, tmp2, gnst);
        hipLaunchKernelGGL(gn_apply_kernel, g2496, dim3(256), 0, stream, tmp2, gnst, gn_g, gn_b, th);
    }

    hipLaunchKernelGGL(attn_mfma_kernel, dim3(5, BH_), dim3(512), 0, stream, qh, kh, attn_out);
    hipLaunchKernelGGL(av_mfma_kernel, dim3(10, BH_), dim3(256), 0, stream, attn_out, vh, ctx);
    hipLaunchKernelGGL((mfma_gemm_bw<true>), dim3(8, 78), dim3(256), 0, stream,
                       ctx, wpb, b_proj, (void*)out3, (void*)out3, (void*)out3);
    hipLaunchKernelGGL(norm_kernel, dim3(BC_), dim3(256), 0, stream, out3, out_main);
}

// Round 5
// 1137.506 us; speedup vs baseline: 1.2684x; 1.0009x over previous
//
#include <hip/hip_runtime.h>
#include <hip/hip_bf16.h>
#include <float.h>

typedef __hip_bfloat16 bf16;
typedef __attribute__((ext_vector_type(8))) __bf16 bfrag;   // MFMA A/B operand (4 VGPRs)
typedef __attribute__((ext_vector_type(4))) float f32x4;    // MFMA C/D operand

#define B_ 32
#define C_ 312
#define N_ 1024
#define H_ 8
#define D_ 128
#define SD_ 78
#define BC_ (B_ * C_)      // 9984
#define BH_ (B_ * H_)      // 256

__device__ __forceinline__ float bf2f(bf16 x) { return __bfloat162float(x); }
__device__ __forceinline__ bf16 f2bf(float x) { return __float2bfloat16(x); }
__device__ __forceinline__ float hswish(float x) {
    return x * fminf(fmaxf(x + 3.0f, 0.0f), 6.0f) * (1.0f / 6.0f);
}

__device__ __forceinline__ void gload_lds16(const void* g, void* l) {
    __builtin_amdgcn_global_load_lds(
        (const __attribute__((address_space(1))) void*)g,
        (__attribute__((address_space(3))) void*)l, 16, 0, 0);
}

// ---------------- LayerNorm (stats only; affine folded into W) --------------
__global__ void ln_kernel(const float* __restrict__ x, bf16* __restrict__ xn) {
    int r = blockIdx.x;
    int t = threadIdx.x;
    const float* xr = x + (size_t)r * N_;
    float s = 0.f, sq = 0.f;
    for (int i = t; i < N_; i += 256) { float f = xr[i]; s += f; sq += f * f; }
    __shared__ float rs[256], rq[256];
    rs[t] = s; rq[t] = sq; __syncthreads();
    for (int o = 128; o > 0; o >>= 1) {
        if (t < o) { rs[t] += rs[t + o]; rq[t] += rq[t + o]; }
        __syncthreads();
    }
    float mu = rs[0] * (1.0f / N_);
    float var = rq[0] * (1.0f / N_) - mu * mu;
    float rstd = rsqrtf(var + 1e-5f);
    bf16* xo = xn + (size_t)r * N_;
    for (int i = t; i < N_; i += 256) xo[i] = f2bf((xr[i] - mu) * rstd);
}

// ---- W preconvert: fold LN gamma into W (bf16), beta into bias row ---------
__global__ void wcvt_kernel(const float* __restrict__ wq, const float* __restrict__ wk,
                            const float* __restrict__ wv, const float* __restrict__ wp,
                            const float* __restrict__ gq, const float* __restrict__ bq,
                            const float* __restrict__ gk, const float* __restrict__ bk,
                            const float* __restrict__ gv, const float* __restrict__ bv_,
                            bf16* __restrict__ wqkv, float* __restrict__ bias3,
                            bf16* __restrict__ wpb) {
    int n = blockIdx.x;          // 0..4095
    int t = threadIdx.x;         // 256
    int k4 = t * 4;
    const float* src; const float* G = nullptr; const float* Bv = nullptr;
    if (n < 1024)      { src = wq + (size_t)n * N_;          G = gq; Bv = bq; }
    else if (n < 2048) { src = wk + (size_t)(n - 1024) * N_; G = gk; Bv = bk; }
    else if (n < 3072) { src = wv + (size_t)(n - 2048) * N_; G = gv; Bv = bv_; }
    else               { src = wp + (size_t)(n - 3072) * N_; }
    float4 w4 = *reinterpret_cast<const float4*>(src + k4);
    if (G) {
        __bf16 o[4] = { (__bf16)(w4.x * G[k4]),     (__bf16)(w4.y * G[k4 + 1]),
                        (__bf16)(w4.z * G[k4 + 2]), (__bf16)(w4.w * G[k4 + 3]) };
        *reinterpret_cast<uint2*>(wqkv + (size_t)n * N_ + k4) = *reinterpret_cast<const uint2*>(o);
        float s = w4.x * Bv[k4] + w4.y * Bv[k4 + 1] + w4.z * Bv[k4 + 2] + w4.w * Bv[k4 + 3];
        __shared__ float rs[256];
        rs[t] = s; __syncthreads();
        for (int o2 = 128; o2 > 0; o2 >>= 1) {
            if (t < o2) rs[t] += rs[t + o2];
            __syncthreads();
        }
        if (t == 0) bias3[n] = rs[0];
    } else {
        __bf16 o[4] = { (__bf16)w4.x, (__bf16)w4.y, (__bf16)w4.z, (__bf16)w4.w };
        *reinterpret_cast<uint2*>(wpb + (size_t)(n - 3072) * N_ + k4) = *reinterpret_cast<const uint2*>(o);
    }
}

// ---------------- MFMA GEMM v3: global_load_lds + XOR-swizzled LDS ----------
// Linear LDS [128][64] bf16 per operand (32 KB total -> 5 blocks/CU).
// Staging: global_load_lds dwordx4, per-lane pre-swizzled global source
// c8s = (l&7)^(l>>3) (row&7 == l>>3 per lane). Read: chunk = row*8 +
// ((kk*4+quad)^(row&7)) -> banks 4*(c8^(l15&7)), 2 lanes/bank = free.
// grid.x linearized (nTx * 78 blocks), XCD-chunked bijective swizzle.
template <bool OUTF32>
__global__ __launch_bounds__(256) void mfma_gemm_bw(
        const bf16* __restrict__ A_,
        const bf16* __restrict__ Wb,
        const float* __restrict__ bias, int nTx,
        void* __restrict__ O0, void* __restrict__ O1, void* __restrict__ O2) {
    const int K = 1024, Nout = 1024;
    __shared__ __bf16 sA[128 * 64];
    __shared__ __bf16 sB[128 * 64];
    const __bf16* A = reinterpret_cast<const __bf16*>(A_);
    const __bf16* W = reinterpret_cast<const __bf16*>(Wb);

    int t = threadIdx.x;
    int lane = t & 63, wave = t >> 6;
    int wm = (wave >> 1) * 64, wn = (wave & 1) * 64;
    int quad = lane >> 4, l15 = lane & 15;

    // XCD-chunked bijective swizzle (nwg % 8 == 0 for 1872 and 624)
    int cpx = gridDim.x >> 3;
    int tile = (blockIdx.x & 7) * cpx + (blockIdx.x >> 3);
    int bx = tile % nTx, by = tile / nTx;
    int m0 = by * 128;
    int w0 = bx * 128;              // W row base (global)
    int which = bx >> 3;
    int n0 = (bx & 7) * 128;        // col within selected output buffer

    // per-lane staging constants
    int rowLoc = wave * 8 + (lane >> 3);          // + cc*32 per instr
    int c8s = (lane & 7) ^ (lane >> 3);           // swizzled source chunk
    const __bf16* gA = A + (size_t)(m0 + rowLoc) * K + c8s * 8;
    const __bf16* gW = W + (size_t)(w0 + rowLoc) * K + c8s * 8;

    f32x4 acc[4][4];
#pragma unroll
    for (int i = 0; i < 4; i++)
#pragma unroll
        for (int j = 0; j < 4; j++) acc[i][j] = (f32x4)(0.f);

    for (int kt = 0; kt < 16; kt++) {
        int k0 = kt * 64;
#pragma unroll
        for (int cc = 0; cc < 4; cc++) {
            gload_lds16(gA + (size_t)cc * 32 * K + k0, &sA[cc * 2048 + wave * 512]);
            gload_lds16(gW + (size_t)cc * 32 * K + k0, &sB[cc * 2048 + wave * 512]);
        }
        __syncthreads();
#pragma unroll
        for (int kk = 0; kk < 2; kk++) {
            bfrag af[4], bfr[4];
#pragma unroll
            for (int mt = 0; mt < 4; mt++) {
                int row = wm + mt * 16 + l15;
                af[mt] = *reinterpret_cast<const bfrag*>(
                    &sA[(row * 8 + ((kk * 4 + quad) ^ (row & 7))) * 8]);
            }
#pragma unroll
            for (int nt = 0; nt < 4; nt++) {
                int row = wn + nt * 16 + l15;
                bfr[nt] = *reinterpret_cast<const bfrag*>(
                    &sB[(row * 8 + ((kk * 4 + quad) ^ (row & 7))) * 8]);
            }
#pragma unroll
            for (int mt = 0; mt < 4; mt++)
#pragma unroll
                for (int nt = 0; nt < 4; nt++)
                    acc[mt][nt] = __builtin_amdgcn_mfma_f32_16x16x32_bf16(af[mt], bfr[nt], acc[mt][nt], 0, 0, 0);
        }
        __syncthreads();
    }
    void* Cout = which == 0 ? O0 : (which == 1 ? O1 : O2);
#pragma unroll
    for (int mt = 0; mt < 4; mt++) {
#pragma unroll
        for (int nt = 0; nt < 4; nt++) {
            int cloc = wn + nt * 16 + l15;
            float bb = bias ? bias[w0 + cloc] : 0.f;
            int col = n0 + cloc;
#pragma unroll
            for (int r = 0; r < 4; r++) {
                int row = m0 + wm + mt * 16 + quad * 4 + r;
                float v = acc[mt][nt][r] + bb;
                if (OUTF32) ((float*)Cout)[(size_t)row * Nout + col] = v;
                else        ((bf16*)Cout)[(size_t)row * Nout + col] = f2bf(v);
            }
        }
    }
}

// ---------------- aggregator pieces -----------------------------------------
__global__ void seg0_kernel(const bf16* __restrict__ t, bf16* __restrict__ th,
                            const float* __restrict__ g, const float* __restrict__ b,
                            const float* __restrict__ m, const float* __restrict__ v) {
    int bc = blockIdx.x;
    int bi = bc / SD_, c = bc % SD_;
    float inv = g[c] * rsqrtf(v[c] + 1e-5f);
    float mm = m[c], bb = b[c];
    const bf16* tp = t + ((size_t)bi * C_ + c) * N_;
    bf16* base = th + (size_t)bi * H_ * C_ * D_;
    for (int n = threadIdx.x; n < N_; n += 256) {
        float y = hswish((bf2f(tp[n]) - mm) * inv + bb);
        base[((n >> 7) * C_ + c) * D_ + (n & 127)] = f2bf(y);
    }
}

template <int KS>
__global__ void dw_kernel(const bf16* __restrict__ t, int cOff,
                          const float* __restrict__ dw, float* __restrict__ outp) {
    int bc = blockIdx.x;
    int bi = bc / SD_, c = bc % SD_;
    const bf16* tp = t + ((size_t)bi * C_ + cOff + c) * N_;
    float w[KS * KS];
#pragma unroll
    for (int q = 0; q < KS * KS; q++) w[q] = dw[c * KS * KS + q];
    float* op = outp + ((size_t)bi * SD_ + c) * N_;
    const int P = KS / 2;
    for (int n = threadIdx.x; n < N_; n += 256) {
        int i = n >> 5, j = n & 31;
        float acc = 0.f;
#pragma unroll
        for (int di = 0; di < KS; di++) {
            int ii = i + di - P;
            if (ii < 0 || ii > 31) continue;
#pragma unroll
            for (int dj = 0; dj < KS; dj++) {
                int jj = j + dj - P;
                if (jj < 0 || jj > 31) continue;
                acc += bf2f(tp[ii * 32 + jj]) * w[di * KS + dj];
            }
        }
        op[n] = acc;
    }
}

template <int MODE>
__global__ void pw_kernel(const float* __restrict__ inp, const float* __restrict__ pw,
                          const float* __restrict__ g, const float* __restrict__ b,
                          const float* __restrict__ m, const float* __restrict__ v,
                          int cOff, bf16* __restrict__ th, float* __restrict__ rawOut) {
    int bo = blockIdx.x;
    int bi = bo / SD_, o = bo % SD_;
    __shared__ float wrow[SD_];
    for (int c = threadIdx.x; c < SD_; c += 256) wrow[c] = pw[o * SD_ + c];
    __syncthreads();
    const float* ip = inp + (size_t)bi * SD_ * N_;
    int t = threadIdx.x;
    float acc[4] = {0.f, 0.f, 0.f, 0.f};
    for (int c = 0; c < SD_; c++) {
        const float* row = ip + (size_t)c * N_;
        float wc = wrow[c];
#pragma unroll
        for (int r = 0; r < 4; r++) acc[r] += row[t + 256 * r] * wc;
    }
    if (MODE == 0) {
        float inv = g[o] * rsqrtf(v[o] + 1e-5f);
        float mm = m[o], bb = b[o];
        bf16* base = th + (size_t)bi * H_ * C_ * D_;
#pragma unroll
        for (int r = 0; r < 4; r++) {
            int n = t + 256 * r;
            float y = hswish((acc[r] - mm) * inv + bb);
            base[((n >> 7) * C_ + cOff + o) * D_ + (n & 127)] = f2bf(y);
        }
    } else {
        float* opr = rawOut + ((size_t)bi * SD_ + o) * N_;
#pragma unroll
        for (int r = 0; r < 4; r++) opr[t + 256 * r] = acc[r];
    }
}

__global__ void gn_stats_kernel(const float* __restrict__ tmp2, float* __restrict__ stats) {
    int bg = blockIdx.x;
    int bi = bg >> 1, grp = bg & 1;
    const float* p = tmp2 + (size_t)bi * SD_ * N_ + (size_t)grp * 39 * N_;
    float s = 0.f, sq = 0.f;
    const int TOT = 39 * N_;
    for (int i = threadIdx.x; i < TOT; i += 256) { float f = p[i]; s += f; sq += f * f; }
    __shared__ float rs[256], rq[256];
    rs[threadIdx.x] = s; rq[threadIdx.x] = sq; __syncthreads();
    for (int o = 128; o > 0; o >>= 1) {
        if (threadIdx.x < o) { rs[threadIdx.x] += rs[threadIdx.x + o]; rq[threadIdx.x] += rq[threadIdx.x + o]; }
        __syncthreads();
    }
    if (threadIdx.x == 0) {
        float mu = rs[0] / (float)TOT;
        float var = rq[0] / (float)TOT - mu * mu;
        stats[bg * 2] = mu;
        stats[bg * 2 + 1] = rsqrtf(var + 1e-5f);
    }
}

__global__ void gn_apply_kernel(const float* __restrict__ tmp2, const float* __restrict__ stats,
                                const float* __restrict__ gg, const float* __restrict__ gb,
                                bf16* __restrict__ th) {
    int bc = blockIdx.x;
    int bi = bc / SD_, c = bc % SD_;
    int grp = c / 39;
    float mu = stats[(bi * 2 + grp) * 2];
    float rstd = stats[(bi * 2 + grp) * 2 + 1];
    float sc = gg[c] * rstd;
    float of = gb[c] - mu * sc;
    const float* p = tmp2 + ((size_t)bi * SD_ + c) * N_;
    bf16* base = th + (size_t)bi * H_ * C_ * D_;
    for (int n = threadIdx.x; n < N_; n += 256) {
        float y = hswish(p[n] * sc + of);
        base[((n >> 7) * C_ + 234 + c) * D_ + (n & 127)] = f2bf(y);
    }
}

// ---- MFMA scores + GELU + scale + softmax, fused ---------------------------
#define SLDA 136
__global__ __launch_bounds__(512, 4) void attn_mfma_kernel(
        const bf16* __restrict__ qh_, const bf16* __restrict__ kh_,
        float* __restrict__ attnOut) {
    __shared__ __bf16 sQ[64 * SLDA];
    __shared__ __bf16 sK[160 * SLDA];
    __shared__ float smax[64][2];
    __shared__ float ssum[64][2];
    const __bf16* qh = reinterpret_cast<const __bf16*>(qh_);
    const __bf16* kh = reinterpret_cast<const __bf16*>(kh_);

    int strip = blockIdx.x;     // 5 strips of 64 Q-rows
    int bh = blockIdx.y;
    int t = threadIdx.x;
    int lane = t & 63, wave = t >> 6;   // 8 waves
    int quad = lane >> 4, l15 = lane & 15;
    int wm = wave >> 1;         // 0..3: 16-row m-tile
    int wn = wave & 1;          // 0..1: 160-col half assignment

#pragma unroll
    for (int cc = 0; cc < 2; cc++) {
        int c = t + cc * 512;
        int row = c >> 4, seg = c & 15;
        int src = strip * 64 + row; if (src > 311) src = 311;
        bfrag v = *reinterpret_cast<const bfrag*>(qh + ((size_t)bh * C_ + src) * D_ + seg * 8);
        *reinterpret_cast<bfrag*>(&sQ[row * SLDA + seg * 8]) = v;
    }

    f32x4 acc[10];
#pragma unroll
    for (int i = 0; i < 10; i++) acc[i] = (f32x4)(0.f);

    bfrag af[4];
    bool afLoaded = false;

    for (int half = 0; half < 2; half++) {
        if (half) __syncthreads();
        for (int cc = 0; cc < 5; cc++) {
            int c = t + cc * 512;
            int row = c >> 4, seg = c & 15;
            int src = half * 160 + row;
            bfrag v;
            if (src < C_) {
                v = *reinterpret_cast<const bfrag*>(kh + ((size_t)bh * C_ + src) * D_ + seg * 8);
            } else {
#pragma unroll
                for (int j = 0; j < 8; j++) v[j] = (__bf16)0.f;
            }
            *reinterpret_cast<bfrag*>(&sK[row * SLDA + seg * 8]) = v;
        }
        __syncthreads();
        if (!afLoaded) {
#pragma unroll
            for (int ks = 0; ks < 4; ks++)
                af[ks] = *reinterpret_cast<const bfrag*>(&sQ[(wm * 16 + l15) * SLDA + ks * 32 + quad * 8]);
            afLoaded = true;
        }
#pragma unroll
        for (int ks = 0; ks < 4; ks++) {
#pragma unroll
            for (int jj = 0; jj < 5; jj++) {
                int lr = (wn * 5 + jj) * 16 + l15;
                bfrag bf = *reinterpret_cast<const bfrag*>(&sK[lr * SLDA + ks * 32 + quad * 8]);
                acc[half * 5 + jj] = __builtin_amdgcn_mfma_f32_16x16x32_bf16(af[ks], bf, acc[half * 5 + jj], 0, 0, 0);
            }
        }
    }

    const float scale = 0.08838834764831845f;
    const float inv_sqrt2 = 0.7071067811865475f;
#pragma unroll
    for (int a = 0; a < 10; a++) {
        int gt = (a / 5) * 10 + wn * 5 + (a % 5);
        int col = gt * 16 + l15;
#pragma unroll
        for (int r = 0; r < 4; r++) {
            float v = acc[a][r];
            float ge = 0.5f * v * (1.0f + erff(v * inv_sqrt2));
            float s = ge * scale;
            if (col >= C_) s = -FLT_MAX;
            acc[a][r] = s;
        }
    }
    float mx[4];
#pragma unroll
    for (int r = 0; r < 4; r++) {
        float m = -FLT_MAX;
#pragma unroll
        for (int a = 0; a < 10; a++) m = fmaxf(m, acc[a][r]);
        for (int o = 1; o < 16; o <<= 1) m = fmaxf(m, __shfl_xor(m, o));
        mx[r] = m;
    }
    if (l15 == 0) {
#pragma unroll
        for (int r = 0; r < 4; r++) smax[wm * 16 + quad * 4 + r][wn] = mx[r];
    }
    __syncthreads();
    float sm[4];
#pragma unroll
    for (int r = 0; r < 4; r++) {
        int row = wm * 16 + quad * 4 + r;
        float m = fmaxf(smax[row][0], smax[row][1]);
        float s = 0.f;
#pragma unroll
        for (int a = 0; a < 10; a++) {
            float e = __expf(acc[a][r] - m);
            acc[a][r] = e;
            s += e;
        }
        for (int o = 1; o < 16; o <<= 1) s += __shfl_xor(s, o);
        sm[r] = s;
    }
    if (l15 == 0) {
#pragma unroll
        for (int r = 0; r < 4; r++) ssum[wm * 16 + quad * 4 + r][wn] = sm[r];
    }
    __syncthreads();
#pragma unroll
    for (int r = 0; r < 4; r++) {
        int row = wm * 16 + quad * 4 + r;
        float inv = 1.0f / (ssum[row][0] + ssum[row][1]);
        int grow = strip * 64 + row;
        if (grow >= C_) continue;
        float* ao = attnOut + ((size_t)bh * C_ + grow) * C_;
#pragma unroll
        for (int a = 0; a < 10; a++) {
            int gt = (a / 5) * 10 + wn * 5 + (a % 5);
            int col = gt * 16 + l15;
            if (col < C_) ao[col] = acc[a][r] * inv;
        }
    }
}

// ---- MFMA attn @ V -> ctx (scrambled layout) --------------------------------
#define PLDA 328   // 320 + 8 pad
__global__ __launch_bounds__(256) void av_mfma_kernel(
        const float* __restrict__ attn, const bf16* __restrict__ vh_,
        bf16* __restrict__ ctx) {
    __shared__ __bf16 sP[32 * PLDA];        // 20992 B
    __shared__ __bf16 sV[2 * 8 * 64 * 8];   // 16384 B  [(ktl,nt,lane) x 8]
    const __bf16* vh = reinterpret_cast<const __bf16*>(vh_);
    int strip = blockIdx.x;                 // 0..9 -> rows strip*32..+31
    int bh = blockIdx.y;
    int t = threadIdx.x;
    int lane = t & 63, wave = t >> 6;
    int quad = lane >> 4, l15 = lane & 15;
    int mt = wave & 1;
    int nh = wave >> 1;

    for (int g = t; g < 32 * 80; g += 256) {
        int row = g / 80, col4 = g % 80;
        int src = strip * 32 + row; if (src > 311) src = 311;
        __bf16 pk[4];
        if (col4 < 78) {
            float4 a4 = *reinterpret_cast<const float4*>(attn + ((size_t)bh * C_ + src) * C_ + col4 * 4);
            pk[0] = (__bf16)a4.x; pk[1] = (__bf16)a4.y; pk[2] = (__bf16)a4.z; pk[3] = (__bf16)a4.w;
        } else {
            pk[0] = pk[1] = pk[2] = pk[3] = (__bf16)0.f;
        }
        *reinterpret_cast<uint2*>(&sP[row * PLDA + col4 * 4]) = *reinterpret_cast<const uint2*>(pk);
    }

    f32x4 acc[4];
#pragma unroll
    for (int i = 0; i < 4; i++) acc[i] = (f32x4)(0.f);

    auto stageV = [&](int chunk) {
#pragma unroll
        for (int it = 0; it < 4; it++) {
            int g = t + it * 256;
            int d = g & 127;
            int oct = g >> 7;
            int ktl = oct >> 2, quad2 = oct & 3;
            int cb = chunk * 64 + ktl * 32 + quad2 * 8;
            const __bf16* vp = vh + ((size_t)bh * C_ + cb) * D_ + d;
            bfrag v;
            if (cb + 7 < C_) {
#pragma unroll
                for (int j = 0; j < 8; j++) v[j] = vp[(size_t)j * D_];
            } else {
#pragma unroll
                for (int j = 0; j < 8; j++) v[j] = (cb + j < C_) ? vp[(size_t)j * D_] : (__bf16)0.f;
            }
            *reinterpret_cast<bfrag*>(&sV[(((ktl * 8 + (d >> 4)) * 64) + quad2 * 16 + (d & 15)) * 8]) = v;
        }
    };

    stageV(0);
    __syncthreads();

    for (int chunk = 0; chunk < 5; chunk++) {
#pragma unroll
        for (int ktl = 0; ktl < 2; ktl++) {
            bfrag a = *reinterpret_cast<const bfrag*>(
                &sP[(mt * 16 + l15) * PLDA + chunk * 64 + ktl * 32 + quad * 8]);
#pragma unroll
            for (int ntl = 0; ntl < 4; ntl++) {
                int ntg = nh * 4 + ntl;
                bfrag b = *reinterpret_cast<const bfrag*>(&sV[(((ktl * 8 + ntg) * 64) + lane) * 8]);
                acc[ntl] = __builtin_amdgcn_mfma_f32_16x16x32_bf16(a, b, acc[ntl], 0, 0, 0);
            }
        }
        if (chunk < 4) {
            __syncthreads();
            stageV(chunk + 1);
            __syncthreads();
        }
    }

    int b = bh >> 3, h = bh & 7;
#pragma unroll
    for (int ntl = 0; ntl < 4; ntl++) {
        int d = nh * 64 + ntl * 16 + l15;
#pragma unroll
        for (int r = 0; r < 4; r++) {
            int c = strip * 32 + mt * 16 + quad * 4 + r;
            if (c < C_) {
                size_t oi = ((size_t)b * C_ + h * 39 + (c >> 3)) * N_ + ((c & 7) << 7) + d;
                ctx[oi] = f2bf(acc[ntl][r]);
            }
        }
    }
}

// ---------------- L2 row norm (fp32 out) -------------------------------------
__global__ void norm_kernel(const float* __restrict__ out3, float* __restrict__ outp) {
    int r = blockIdx.x;
    const float* p = out3 + (size_t)r * N_;
    float sq = 0.f;
    for (int i = threadIdx.x; i < N_; i += 256) { float f = p[i]; sq += f * f; }
    __shared__ float rq[256];
    rq[threadIdx.x] = sq; __syncthreads();
    for (int o = 128; o > 0; o >>= 1) {
        if (threadIdx.x < o) rq[threadIdx.x] += rq[threadIdx.x + o];
        __syncthreads();
    }
    float inv = 1.0f / fmaxf(sqrtf(rq[0]), 1e-12f);
    float* po = outp + (size_t)r * N_;
    for (int i = threadIdx.x; i < N_; i += 256) po[i] = p[i] * inv;
}

// ---------------- host orchestration ----------------------------------------
extern "C" void kernel_launch(void* const* d_in, const int* in_sizes, int n_in,
                              void* d_out, int out_size, void* d_ws, size_t ws_size,
                              hipStream_t stream) {
    const float* x      = (const float*)d_in[0];
    const float* ln_q_g = (const float*)d_in[3];
    const float* ln_q_b = (const float*)d_in[4];
    const float* ln_k_g = (const float*)d_in[5];
    const float* ln_k_b = (const float*)d_in[6];
    const float* ln_v_g = (const float*)d_in[7];
    const float* ln_v_b = (const float*)d_in[8];
    const float* w_q    = (const float*)d_in[9];
    const float* w_k    = (const float*)d_in[10];
    const float* w_v    = (const float*)d_in[11];
    const float* w_proj = (const float*)d_in[12];
    const float* b_proj = (const float*)d_in[13];
    const float* dw0    = (const float*)d_in[14];
    const float* pw0    = (const float*)d_in[15];
    const float* gn_g   = (const float*)d_in[16];
    const float* gn_b   = (const float*)d_in[17];
    const float* dw1    = (const float*)d_in[18];
    const float* pw1    = (const float*)d_in[19];
    const float* dw2    = (const float*)d_in[20];
    const float* pw2    = (const float*)d_in[21];
    const float* bn0_g  = (const float*)d_in[22];
    const float* bn0_b  = (const float*)d_in[23];
    const float* bn0_m  = (const float*)d_in[24];
    const float* bn0_v  = (const float*)d_in[25];
    const float* bn1_g  = (const float*)d_in[26];
    const float* bn1_b  = (const float*)d_in[27];
    const float* bn1_m  = (const float*)d_in[28];
    const float* bn1_v  = (const float*)d_in[29];
    const float* bn2_g  = (const float*)d_in[30];
    const float* bn2_b  = (const float*)d_in[31];
    const float* bn2_m  = (const float*)d_in[32];
    const float* bn2_v  = (const float*)d_in[33];

    char* ws = (char*)d_ws;
    size_t off = 0;
    auto alloc = [&](size_t bytes) {
        void* p = ws + off;
        off = (off + bytes + 255) & ~(size_t)255;
        return p;
    };
    const size_t BF_BYTES = (size_t)BC_ * N_ * sizeof(bf16);
    bf16*  xn   = (bf16*)alloc(BF_BYTES);
    bf16*  qb   = (bf16*)alloc(BF_BYTES);
    bf16*  kb   = (bf16*)alloc(BF_BYTES);
    bf16*  vb   = (bf16*)alloc(BF_BYTES);
    float* tmp1 = (float*)alloc((size_t)B_ * SD_ * N_ * sizeof(float));
    float* tmp2 = (float*)alloc((size_t)B_ * SD_ * N_ * sizeof(float));
    float* gnst = (float*)alloc(512);
    bf16*  wqkv = (bf16*)alloc((size_t)3 * N_ * N_ * sizeof(bf16));   // 6 MB
    float* bias3 = (float*)alloc((size_t)3 * N_ * sizeof(float));
    bf16*  wpb  = (bf16*)alloc((size_t)N_ * N_ * sizeof(bf16));       // 2 MB
    bf16* qh  = xn;
    bf16* kh  = qb;
    bf16* vh  = kb;
    bf16* ctx = vb;
    float* out3 = (float*)xn;   // aliases xn+qb (dead after attn/av)

    float* out_main = (float*)d_out;
    float* attn_out = out_main + (size_t)BC_ * N_;

    hipLaunchKernelGGL(wcvt_kernel, dim3(4096), dim3(256), 0, stream,
                       w_q, w_k, w_v, w_proj,
                       ln_q_g, ln_q_b, ln_k_g, ln_k_b, ln_v_g, ln_v_b,
                       wqkv, bias3, wpb);
    hipLaunchKernelGGL(ln_kernel, dim3(BC_), dim3(256), 0, stream, x, xn);
    hipLaunchKernelGGL((mfma_gemm_bw<false>), dim3(24 * 78), dim3(256), 0, stream,
                       xn, wqkv, bias3, 24, (void*)qb, (void*)kb, (void*)vb);

    const bf16* tins[3] = {qb, kb, vb};
    bf16* thouts[3] = {qh, kh, vh};
    for (int i = 0; i < 3; i++) {
        const bf16* t = tins[i];
        bf16* th = thouts[i];
        dim3 g2496(B_ * SD_);
        hipLaunchKernelGGL(seg0_kernel, g2496, dim3(256), 0, stream,
                           t, th, bn0_g, bn0_b, bn0_m, bn0_v);
        hipLaunchKernelGGL((dw_kernel<3>), g2496, dim3(256), 0, stream, t, SD_, dw1, tmp1);
        hipLaunchKernelGGL((pw_kernel<0>), g2496, dim3(256), 0, stream,
                           tmp1, pw1, bn1_g, bn1_b, bn1_m, bn1_v, SD_, th, (float*)nullptr);
        hipLaunchKernelGGL((dw_kernel<5>), g2496, dim3(256), 0, stream, t, 2 * SD_, dw2, tmp1);
        hipLaunchKernelGGL((pw_kernel<0>), g2496, dim3(256), 0, stream,
                           tmp1, pw2, bn2_g, bn2_b, bn2_m, bn2_v, 2 * SD_, th, (float*)nullptr);
        hipLaunchKernelGGL((dw_kernel<3>), g2496, dim3(256), 0, stream, t, 3 * SD_, dw0, tmp1);
        hipLaunchKernelGGL((pw_kernel<1>), g2496, dim3(256), 0, stream,
                           tmp1, pw0, (const float*)nullptr, (const float*)nullptr,
                           (const float*)nullptr, (const float*)nullptr, 0, (bf16*)nullptr, tmp2);
        hipLaunchKernelGGL(gn_stats_kernel, dim3(B_ * 2), dim3(256), 0, stream, tmp2, gnst);
        hipLaunchKernelGGL(gn_apply_kernel, g2496, dim3(256), 0, stream, tmp2, gnst, gn_g, gn_b, th);
    }

    hipLaunchKernelGGL(attn_mfma_kernel, dim3(5, BH_), dim3(512), 0, stream, qh, kh, attn_out);
    hipLaunchKernelGGL(av_mfma_kernel, dim3(10, BH_), dim3(256), 0, stream, attn_out, vh, ctx);
    hipLaunchKernelGGL((mfma_gemm_bw<true>), dim3(8 * 78), dim3(256), 0, stream,
                       ctx, wpb, b_proj, 8, (void*)out3, (void*)out3, (void*)out3);
    hipLaunchKernelGGL(norm_kernel, dim3(BC_), dim3(256), 0, stream, out3, out_main);
}